// Round 15
// baseline (89.941 us; speedup 1.0000x reference)
//
#include <hip/hip_runtime.h>
#include <hip/hip_bf16.h>

#define NB 64
#define NN 512
#define CI 32
#define CO 64
#define XN 68
// Ybf layout: [b][kb=0..15][row=0..79][40], bf16, pre-scaled by c0/n; cols 32..39 = 0 pad
//   (pad lives in GLOBAL layout so global_load_lds produces conflict-free 80B-stride LDS rows).
// Abf layout: [b][ic=0..7][c=0..7][4096], bf16(A) in k5 fragment-linear order:
//   element (local row r 0..63, kk 0..63) at r*64 + (((kk>>3) ^ (r&7))<<3) + (kk&7).

typedef __attribute__((ext_vector_type(8))) short bf16x8;
typedef __attribute__((ext_vector_type(4))) float f32x4;

__device__ inline short f2bf(float f) {
  union { __hip_bfloat16 h; unsigned short u; } cv;
  cv.h = __float2bfloat16(f);
  return (short)cv.u;
}

__device__ inline bf16x8 cvt8(float4 a, float4 b) {
  bf16x8 r;
  r[0] = f2bf(a.x); r[1] = f2bf(a.y); r[2] = f2bf(a.z); r[3] = f2bf(a.w);
  r[4] = f2bf(b.x); r[5] = f2bf(b.y); r[6] = f2bf(b.z); r[7] = f2bf(b.w);
  return r;
}

__device__ __forceinline__ void gld16(const void* g, void* l) {
  __builtin_amdgcn_global_load_lds(
      (const __attribute__((address_space(1))) unsigned int*)g,
      (__attribute__((address_space(3))) unsigned int*)l, 16, 0, 0);
}

// ---------------- K1X: A row stats + X stats + Ybf chunk + Abf. grid (NB,32) ----------------
__global__ __launch_bounds__(256) void k1x(
    const float* __restrict__ A, const float* __restrict__ X,
    const float* __restrict__ cf, const float* __restrict__ W1,
    float* __restrict__ mc, float* __restrict__ dg, float* __restrict__ vec,
    float* __restrict__ pA, float* __restrict__ pD,
    float* __restrict__ pmX, float* __restrict__ ptC, float* __restrict__ pS,
    unsigned short* __restrict__ Ybf, unsigned short* __restrict__ Abf) {
  int b = blockIdx.x, ch = blockIdx.y;
  int t = threadIdx.x, w = t >> 6, lane = t & 63;
  int r0 = ch * 16;
  int kb = r0 >> 5, jbase = r0 & 16;
  const float* Ab = A + (size_t)b * NN * NN;
  __shared__ float sXc[16][33];
  __shared__ float scf[69];
  __shared__ float sMc[16], sDg[16], sVec[16], wsum[4];

  if (t < 69) scf[t] = cf[t];
  {  // stage X chunk: 16 rows x 32 cols
    int j = t >> 4, c = (t & 15) * 2;
    float2 xv = *(const float2*)(X + ((size_t)b * NN + r0 + j) * CI + c);
    sXc[j][c] = xv.x; sXc[j][c + 1] = xv.y;
  }
  float4 v0[4], v1[4];
#pragma unroll
  for (int m = 0; m < 4; ++m) {
    const float* rp = Ab + (size_t)(r0 + w * 4 + m) * NN;
    v0[m] = *(const float4*)(rp + lane * 4);
    v1[m] = *(const float4*)(rp + 256 + lane * 4);
  }
  float accR = 0.f;
#pragma unroll
  for (int m = 0; m < 4; ++m) {
    float s = (v0[m].x + v0[m].y) + (v0[m].z + v0[m].w) +
              (v1[m].x + v1[m].y) + (v1[m].z + v1[m].w);
#pragma unroll
    for (int off = 1; off < 64; off <<= 1) s += __shfl_xor(s, off, 64);
    if (lane == 0) {
      float m_ = s * (1.0f / NN);
      mc[b * NN + r0 + w * 4 + m] = m_;
      sMc[w * 4 + m] = m_;
    }
    accR += s;
  }
  if (lane == 0) wsum[w] = accR;
  if (t < 16) {
    float d = Ab[(size_t)(r0 + t) * NN + r0 + t];
    dg[b * NN + r0 + t] = d;
    sDg[t] = d;
  }

  {  // Abf: bf16(A) in k5-fragment-linear order
    int ic5 = ch >> 2;
    int lrb = (ch & 3) * 16 + w * 4;
    size_t bb = ((size_t)(b * 8 + ic5)) * 8 * 4096;
    int c5a = lane >> 4;
    int Ka = (lane & 15) >> 1;
    int sub = (lane & 1) << 2;
#pragma unroll
    for (int m = 0; m < 4; ++m) {
      int lr = lrb + m;
      int sl = ((Ka ^ (lr & 7)) << 3) + sub;
      union { unsigned short u[4]; uint2 v; } p0, p1;
      p0.u[0] = (unsigned short)f2bf(v0[m].x); p0.u[1] = (unsigned short)f2bf(v0[m].y);
      p0.u[2] = (unsigned short)f2bf(v0[m].z); p0.u[3] = (unsigned short)f2bf(v0[m].w);
      p1.u[0] = (unsigned short)f2bf(v1[m].x); p1.u[1] = (unsigned short)f2bf(v1[m].y);
      p1.u[2] = (unsigned short)f2bf(v1[m].z); p1.u[3] = (unsigned short)f2bf(v1[m].w);
      *(uint2*)(Abf + bb + (size_t)c5a * 4096 + lr * 64 + sl) = p0.v;
      *(uint2*)(Abf + bb + (size_t)(4 + c5a) * 4096 + lr * 64 + sl) = p1.v;
    }
  }
  __syncthreads();

  float c0n = scf[0] * (1.0f / NN);

  if (t < 16) {
    float u = 0.f;
#pragma unroll
    for (int c = 0; c < CI; ++c) u += scf[5 + c] * sXc[t][c];
    float vj = scf[3] * sMc[t] + scf[4] * sDg[t] + u;
    vec[b * NN + r0 + t] = vj;
    sVec[t] = vj;
  } else if (t == 16) {
    pA[b * 32 + ch] = wsum[0] + wsum[1] + wsum[2] + wsum[3];
    float sd = 0.f;
#pragma unroll
    for (int k = 0; k < 16; ++k) sd += sDg[k];
    pD[b * 32 + ch] = sd;
  }

  {  // Y chunk via MFMA (scaled by c0/n): wave w -> rows o = w*16..+15, cols r0..+15
    int ra = lane & 15, kg = lane >> 4, g = lane >> 4;
    const float* wp = W1 + (w * 16 + ra) * XN + kg * 8;
    bf16x8 wf = cvt8(*(const float4*)wp, *(const float4*)(wp + 4));
    const float* xp = &sXc[ra][kg * 8];
    bf16x8 xf = cvt8(*(const float4*)xp, *(const float4*)(xp + 4));
    f32x4 zero = {0.f, 0.f, 0.f, 0.f};
    f32x4 d = __builtin_amdgcn_mfma_f32_16x16x32_bf16(xf, wf, zero, 0, 0, 0);
    union { unsigned short u[4]; uint2 v; } pk;
#pragma unroll
    for (int r = 0; r < 4; ++r) pk.u[r] = (unsigned short)f2bf(d[r] * c0n);
    int o = w * 16 + ra;
    *(uint2*)(Ybf + (((size_t)b * 16 + kb) * 80 + o) * 40 + jbase + g * 4) = pk.v;
  }
  // rows 64/65 + zero pad rows 66..79 (this chunk's 16 cols) + col-pad 32..39 (jbase==0 block)
  if (t < 16) {
    Ybf[(((size_t)b * 16 + kb) * 80 + 64) * 40 + jbase + t] =
        (unsigned short)f2bf(sMc[t] * c0n);
  } else if (t < 32) {
    Ybf[(((size_t)b * 16 + kb) * 80 + 65) * 40 + jbase + (t - 16)] =
        (unsigned short)f2bf(sDg[t - 16] * c0n);
  } else if (t < 32 + 224) {
    int u2 = t - 32;
    int row = 66 + (u2 >> 4), col = jbase + (u2 & 15);
    Ybf[(((size_t)b * 16 + kb) * 80 + row) * 40 + col] = 0;
  }
  if (jbase == 0 && t < 80) {
    uint4 z = make_uint4(0u, 0u, 0u, 0u);
    *(uint4*)(Ybf + (((size_t)b * 16 + kb) * 80 + t) * 40 + 32) = z;
  }
  __syncthreads();

  if (t < 32) {
    float s1 = 0.f, s2 = 0.f;
#pragma unroll
    for (int r = 0; r < 16; ++r) {
      float xv = sXc[r][t];
      s1 += xv;
      s2 += sVec[r] * xv;
    }
    pmX[((size_t)b * 32 + ch) * 32 + t] = s1;
    ptC[((size_t)b * 32 + ch) * 32 + t] = s2;
  } else if (t < 35) {
    float s = 0.f;
    if (t == 32) { for (int r = 0; r < 16; ++r) s += sVec[r]; }
    if (t == 33) { for (int r = 0; r < 16; ++r) s += sVec[r] * sMc[r]; }
    if (t == 34) { for (int r = 0; r < 16; ++r) s += sVec[r] * sDg[r]; }
    pS[((size_t)b * 32 + ch) * 3 + (t - 32)] = s;
  }
}

// ---------------- KW: finalize stats -> colv, sconst. grid (16) ----------------
__global__ __launch_bounds__(256) void kW(
    const float* __restrict__ cf, const float* __restrict__ W1,
    const float* __restrict__ W2, const float* __restrict__ pA,
    const float* __restrict__ pD, const float* __restrict__ pmX,
    const float* __restrict__ ptC, const float* __restrict__ pS,
    float* __restrict__ colv, float* __restrict__ sconst) {
  int gb = blockIdx.x, t = threadIdx.x;
  int bb0 = gb * 4;
  __shared__ float sW1[64][69], sW2[64][69];
  __shared__ float mXs[4][33], tCs[4][33];
  __shared__ float scal[4][6];
  __shared__ float scf[69];
  if (t < 69) scf[t] = cf[t];
  for (int idx = t; idx < 64 * XN; idx += 256) {
    int r = idx / XN, c = idx - r * XN;
    sW1[r][c] = W1[idx];
    sW2[r][c] = W2[idx];
  }
  if (t < 128) {
    int bb = t >> 5, c = t & 31, b = bb0 + bb;
    float s1 = 0.f, s2 = 0.f;
#pragma unroll
    for (int k = 0; k < 32; ++k) {
      s1 += pmX[((size_t)b * 32 + k) * 32 + c];
      s2 += ptC[((size_t)b * 32 + k) * 32 + c];
    }
    mXs[bb][c] = s1 * (1.0f / NN);
    tCs[bb][c] = s2;
  } else if (t < 132) {
    int bb = t - 128, b = bb0 + bb;
    float sA = 0.f, sD = 0.f;
#pragma unroll
    for (int k = 0; k < 32; ++k) { sA += pA[b * 32 + k]; sD += pD[b * 32 + k]; }
    scal[bb][0] = sD * (1.0f / NN);
    scal[bb][1] = sA * (1.0f / ((float)NN * (float)NN));
  } else if (t < 136) {
    int bb = t - 132, b = bb0 + bb;
    float s1 = 0.f, s2 = 0.f, s3 = 0.f;
#pragma unroll
    for (int k = 0; k < 32; ++k) {
      s1 += pS[((size_t)b * 32 + k) * 3 + 0];
      s2 += pS[((size_t)b * 32 + k) * 3 + 1];
      s3 += pS[((size_t)b * 32 + k) * 3 + 2];
    }
    scal[bb][2] = s1; scal[bb][3] = s2; scal[bb][4] = s3;
  }
  __syncthreads();
  if (t < 4) {
    float s7 = 0.f;
#pragma unroll
    for (int c = 0; c < CI; ++c) s7 += scf[5 + CI + c] * mXs[t][c];
    sconst[bb0 + t] = scf[1] * scal[t][1] + scf[2] * scal[t][0] + s7;
  }
  {
    int bb = t >> 6, o = t & 63, b = bb0 + bb;
    float w1mX = 0.f, a1 = 0.f, a2 = 0.f, wt = 0.f;
#pragma unroll
    for (int c = 0; c < CI; ++c) {
      float m = mXs[bb][c];
      w1mX += sW1[o][c] * m;
      a1 += sW1[o][CI + c] * m;
      a2 += sW2[o][CI + c] * m;
      wt += sW1[o][c] * tCs[bb][c];
    }
    float smd = scal[bb][0], sma = scal[bb][1];
    a1 += sW1[o][66] * smd + sW1[o][67] * sma;
    a2 += sW2[o][66] * smd + sW2[o][67] * sma;
    float we0 = sW1[o][64], we1 = sW1[o][65];
    float S1n = w1mX + a1 + we0 * sma + we1 * smd;
    float SVn = (wt + a1 * scal[bb][2] + we0 * scal[bb][3] + we1 * scal[bb][4]) * (1.0f / NN);
    float4 cva = make_float4(S1n, a2 + SVn, sW2[o][64] + scf[0] * a1, sW2[o][65]);
    float4 cvb = make_float4(we0, we1, 0.f, 0.f);
    *(float4*)&colv[((size_t)b * CO + o) * 8] = cva;
    *(float4*)&colv[((size_t)b * CO + o) * 8 + 4] = cvb;
  }
}

// ---------------- K5 v6: async staging, padded-B (conflict-free), REP=2 diagnostic ----------------
// grid (8, NB), 512 threads = 8 waves = 4 row-groups x 2 col-halves.
__global__ __launch_bounds__(512, 6) void k5_mfma(
    const unsigned short* __restrict__ Abf, const unsigned short* __restrict__ Ybf,
    const float* __restrict__ X, const float* __restrict__ W2,
    const float* __restrict__ vec, const float* __restrict__ mc,
    const float* __restrict__ dg, const float* __restrict__ colv,
    const float* __restrict__ sconst, float* __restrict__ out) {
  int ic = blockIdx.x, b = blockIdx.y;
  int t = threadIdx.x, w = t >> 6, lane = t & 63;
  int rg = w >> 1, oc = w & 1;
  int ra = lane & 15, kg = lane >> 4, g = lane >> 4;
  int i0 = ic * 64;
  int wr0 = rg * 16;
  __shared__ unsigned short sA[2][4096];   // 8KB/buf, fragment-linear (2-way free)
  __shared__ unsigned short sB[2][6400];   // 12.8KB/buf, rows @ 80B stride (2-way free)
  __shared__ float sGm[64], sGd[64];

  const unsigned short* Asrc = Abf + ((size_t)(b * 8 + ic)) * 8 * 4096;
  const unsigned short* Bsrc = Ybf + (size_t)b * 16 * 80 * 40;

  int aoff = w * 512 + lane * 8;
  int arow = wr0 + ra;
  int abase = arow * 64;
  int aswz = arow & 7;

#pragma unroll 1
  for (int rep = 0; rep < 2; ++rep) {   // REP=2: diagnostic duplication (idempotent)
    {  // prologue: stage chunk 0
      gld16(Asrc + aoff, &sA[0][w * 512]);
      gld16(Bsrc + aoff, &sB[0][w * 512]);
      if (w < 4) gld16(Bsrc + 4096 + w * 512 + lane * 8, &sB[0][4096 + w * 512]);
      if (w == 4 && lane < 32) gld16(Bsrc + 6144 + lane * 8, &sB[0][6144]);
    }
    __syncthreads();

    f32x4 acc[2] = {{0.f, 0.f, 0.f, 0.f}, {0.f, 0.f, 0.f, 0.f}};
    f32x4 acc4 = {0.f, 0.f, 0.f, 0.f};

    for (int c = 0; c < 8; ++c) {
      int cur = c & 1;
      if (c < 7) {  // async-issue next chunk
        const unsigned short* an = Asrc + (size_t)(c + 1) * 4096;
        const unsigned short* bn = Bsrc + (size_t)(c + 1) * 6400;
        gld16(an + aoff, &sA[cur ^ 1][w * 512]);
        gld16(bn + w * 512 + lane * 8, &sB[cur ^ 1][w * 512]);
        if (w < 4) gld16(bn + 4096 + w * 512 + lane * 8, &sB[cur ^ 1][4096 + w * 512]);
        if (w == 4 && lane < 32) gld16(bn + 6144 + lane * 8, &sB[cur ^ 1][6144]);
      }
#pragma unroll
      for (int kbl = 0; kbl < 2; ++kbl) {
        bf16x8 af = *(const bf16x8*)&sA[cur][abase + (((kbl * 4 + kg) ^ aswz) << 3)];
#pragma unroll
        for (int to = 0; to < 2; ++to) {
          int grow = kbl * 80 + oc * 32 + to * 16 + ra;
          bf16x8 bf = *(const bf16x8*)&sB[cur][grow * 40 + kg * 8];
          acc[to] = __builtin_amdgcn_mfma_f32_16x16x32_bf16(af, bf, acc[to], 0, 0, 0);
        }
        if (oc == 0) {
          bf16x8 bf4 = *(const bf16x8*)&sB[cur][(kbl * 80 + 64 + ra) * 40 + kg * 8];
          acc4 = __builtin_amdgcn_mfma_f32_16x16x32_bf16(af, bf4, acc4, 0, 0, 0);
        }
      }
      __syncthreads();
    }

    {  // fused X*W2c k-step (unscaled)
      const float* xp = X + (size_t)(b * NN + i0 + wr0 + ra) * CI + kg * 8;
      bf16x8 xf = cvt8(*(const float4*)xp, *(const float4*)(xp + 4));
#pragma unroll
      for (int to = 0; to < 2; ++to) {
        const float* wp = W2 + (size_t)(oc * 32 + to * 16 + ra) * XN + kg * 8;
        bf16x8 wf = cvt8(*(const float4*)wp, *(const float4*)(wp + 4));
        acc[to] = __builtin_amdgcn_mfma_f32_16x16x32_bf16(xf, wf, acc[to], 0, 0, 0);
      }
    }

    if (oc == 0 && ra < 2) {
#pragma unroll
      for (int r = 0; r < 4; ++r) {
        if (ra == 0) sGm[wr0 + g * 4 + r] = acc4[r];
        else         sGd[wr0 + g * 4 + r] = acc4[r];
      }
    }
    __syncthreads();

    // epilogue
    float4 v4 = *(const float4*)&vec[b * NN + i0 + wr0 + g * 4];
    float4 m4 = *(const float4*)&mc[b * NN + i0 + wr0 + g * 4];
    float4 d4 = *(const float4*)&dg[b * NN + i0 + wr0 + g * 4];
    float sc = sconst[b];
    float vp[4] = {v4.x + sc, v4.y + sc, v4.z + sc, v4.w + sc};
    float mr[4] = {m4.x, m4.y, m4.z, m4.w};
    float dr[4] = {d4.x, d4.y, d4.z, d4.w};
    float Gm[4], Gd[4];
#pragma unroll
    for (int r = 0; r < 4; ++r) {
      int row = wr0 + g * 4 + r;
      Gm[r] = sGm[row];
      Gd[r] = sGd[row];
    }

#pragma unroll
    for (int to = 0; to < 2; ++to) {
      int o = oc * 32 + to * 16 + ra;
      float4 cva = *(const float4*)&colv[((size_t)b * CO + o) * 8];
      float4 cvb = *(const float4*)&colv[((size_t)b * CO + o) * 8 + 4];
#pragma unroll
      for (int r = 0; r < 4; ++r) {
        float val = acc[to][r] + vp[r] * cva.x + cva.y + mr[r] * cva.z +
                    dr[r] * cva.w + Gm[r] * cvb.x + Gd[r] * cvb.y;
        out[((size_t)(b * NN + i0 + wr0 + g * 4 + r)) * CO + o] = val;
      }
    }
    __syncthreads();  // separate reps (sGm/sA rewrite next rep)
  }
}

extern "C" void kernel_launch(void* const* d_in, const int* in_sizes, int n_in,
                              void* d_out, int out_size, void* d_ws, size_t ws_size,
                              hipStream_t stream) {
  const float* A = (const float*)d_in[0];
  const float* X = (const float*)d_in[1];
  const float* cf = (const float*)d_in[2];
  const float* W1 = (const float*)d_in[3];
  const float* W2 = (const float*)d_in[4];
  float* out = (float*)d_out;

  float* p = (float*)d_ws;
  float* mc = p;      p += NB * NN;
  float* dg = p;      p += NB * NN;
  float* vec = p;     p += NB * NN;
  float* pA = p;      p += NB * 32;
  float* pD = p;      p += NB * 32;
  float* pmX = p;     p += NB * 32 * 32;
  float* ptC = p;     p += NB * 32 * 32;
  float* pS = p;      p += NB * 32 * 3;
  float* colv = p;    p += NB * CO * 8;
  float* sconst = p;  p += NB;
  unsigned short* Ybf = (unsigned short*)p;
  unsigned short* Abf = Ybf + (size_t)NB * 16 * 80 * 40;

  k1x<<<dim3(NB, 32), 256, 0, stream>>>(A, X, cf, W1, mc, dg, vec,
                                        pA, pD, pmX, ptC, pS, Ybf, Abf);
  kW<<<16, 256, 0, stream>>>(cf, W1, W2, pA, pD, pmX, ptC, pS, colv, sconst);
  k5_mfma<<<dim3(8, NB), 512, 0, stream>>>(Abf, Ybf, X, W2, vec, mc, dg,
                                           colv, sconst, out);
}

// Round 16
// 47.439 us; speedup vs baseline: 1.8959x; 1.8959x over previous
//
#include <hip/hip_runtime.h>
#include <hip/hip_bf16.h>

#define NB 64
#define NN 512
#define CI 32
#define CO 64
#define XN 68
// Ybf layout: [b][kb=0..15][row=0..79][32], bf16, pre-scaled by c0/n (UNPADDED —
//   k5 reads fragments straight to VGPRs, no LDS banks involved).
// Abf layout: [b][ic=0..7][c=0..7][4096], bf16(A) in k5 fragment-linear order:
//   element (local row r 0..63, kk 0..63) at r*64 + (((kk>>3) ^ (r&7))<<3) + (kk&7).

typedef __attribute__((ext_vector_type(8))) short bf16x8;
typedef __attribute__((ext_vector_type(4))) float f32x4;

__device__ inline short f2bf(float f) {
  union { __hip_bfloat16 h; unsigned short u; } cv;
  cv.h = __float2bfloat16(f);
  return (short)cv.u;
}

__device__ inline bf16x8 cvt8(float4 a, float4 b) {
  bf16x8 r;
  r[0] = f2bf(a.x); r[1] = f2bf(a.y); r[2] = f2bf(a.z); r[3] = f2bf(a.w);
  r[4] = f2bf(b.x); r[5] = f2bf(b.y); r[6] = f2bf(b.z); r[7] = f2bf(b.w);
  return r;
}

// ---------------- K1X: A row stats + X stats + Ybf chunk + Abf. grid (NB,32) ----------------
__global__ __launch_bounds__(256) void k1x(
    const float* __restrict__ A, const float* __restrict__ X,
    const float* __restrict__ cf, const float* __restrict__ W1,
    float* __restrict__ mc, float* __restrict__ dg, float* __restrict__ vec,
    float* __restrict__ pA, float* __restrict__ pD,
    float* __restrict__ pmX, float* __restrict__ ptC, float* __restrict__ pS,
    unsigned short* __restrict__ Ybf, unsigned short* __restrict__ Abf) {
  int b = blockIdx.x, ch = blockIdx.y;
  int t = threadIdx.x, w = t >> 6, lane = t & 63;
  int r0 = ch * 16;
  int kb = r0 >> 5, jbase = r0 & 16;
  const float* Ab = A + (size_t)b * NN * NN;
  __shared__ float sXc[16][33];
  __shared__ float scf[69];
  __shared__ float sMc[16], sDg[16], sVec[16], wsum[4];

  if (t < 69) scf[t] = cf[t];
  {  // stage X chunk: 16 rows x 32 cols
    int j = t >> 4, c = (t & 15) * 2;
    float2 xv = *(const float2*)(X + ((size_t)b * NN + r0 + j) * CI + c);
    sXc[j][c] = xv.x; sXc[j][c + 1] = xv.y;
  }
  float4 v0[4], v1[4];
#pragma unroll
  for (int m = 0; m < 4; ++m) {
    const float* rp = Ab + (size_t)(r0 + w * 4 + m) * NN;
    v0[m] = *(const float4*)(rp + lane * 4);
    v1[m] = *(const float4*)(rp + 256 + lane * 4);
  }
  float accR = 0.f;
#pragma unroll
  for (int m = 0; m < 4; ++m) {
    float s = (v0[m].x + v0[m].y) + (v0[m].z + v0[m].w) +
              (v1[m].x + v1[m].y) + (v1[m].z + v1[m].w);
#pragma unroll
    for (int off = 1; off < 64; off <<= 1) s += __shfl_xor(s, off, 64);
    if (lane == 0) {
      float m_ = s * (1.0f / NN);
      mc[b * NN + r0 + w * 4 + m] = m_;
      sMc[w * 4 + m] = m_;
    }
    accR += s;
  }
  if (lane == 0) wsum[w] = accR;
  if (t < 16) {
    float d = Ab[(size_t)(r0 + t) * NN + r0 + t];
    dg[b * NN + r0 + t] = d;
    sDg[t] = d;
  }

  {  // Abf: bf16(A) in k5-fragment-linear order
    int ic5 = ch >> 2;
    int lrb = (ch & 3) * 16 + w * 4;
    size_t bb = ((size_t)(b * 8 + ic5)) * 8 * 4096;
    int c5a = lane >> 4;
    int Ka = (lane & 15) >> 1;
    int sub = (lane & 1) << 2;
#pragma unroll
    for (int m = 0; m < 4; ++m) {
      int lr = lrb + m;
      int sl = ((Ka ^ (lr & 7)) << 3) + sub;
      union { unsigned short u[4]; uint2 v; } p0, p1;
      p0.u[0] = (unsigned short)f2bf(v0[m].x); p0.u[1] = (unsigned short)f2bf(v0[m].y);
      p0.u[2] = (unsigned short)f2bf(v0[m].z); p0.u[3] = (unsigned short)f2bf(v0[m].w);
      p1.u[0] = (unsigned short)f2bf(v1[m].x); p1.u[1] = (unsigned short)f2bf(v1[m].y);
      p1.u[2] = (unsigned short)f2bf(v1[m].z); p1.u[3] = (unsigned short)f2bf(v1[m].w);
      *(uint2*)(Abf + bb + (size_t)c5a * 4096 + lr * 64 + sl) = p0.v;
      *(uint2*)(Abf + bb + (size_t)(4 + c5a) * 4096 + lr * 64 + sl) = p1.v;
    }
  }
  __syncthreads();

  float c0n = scf[0] * (1.0f / NN);

  if (t < 16) {
    float u = 0.f;
#pragma unroll
    for (int c = 0; c < CI; ++c) u += scf[5 + c] * sXc[t][c];
    float vj = scf[3] * sMc[t] + scf[4] * sDg[t] + u;
    vec[b * NN + r0 + t] = vj;
    sVec[t] = vj;
  } else if (t == 16) {
    pA[b * 32 + ch] = wsum[0] + wsum[1] + wsum[2] + wsum[3];
    float sd = 0.f;
#pragma unroll
    for (int k = 0; k < 16; ++k) sd += sDg[k];
    pD[b * 32 + ch] = sd;
  }

  {  // Y chunk via MFMA (scaled by c0/n): wave w -> rows o = w*16..+15, cols r0..+15
    int ra = lane & 15, kg = lane >> 4, g = lane >> 4;
    const float* wp = W1 + (w * 16 + ra) * XN + kg * 8;
    bf16x8 wf = cvt8(*(const float4*)wp, *(const float4*)(wp + 4));
    const float* xp = &sXc[ra][kg * 8];
    bf16x8 xf = cvt8(*(const float4*)xp, *(const float4*)(xp + 4));
    f32x4 zero = {0.f, 0.f, 0.f, 0.f};
    f32x4 d = __builtin_amdgcn_mfma_f32_16x16x32_bf16(xf, wf, zero, 0, 0, 0);
    union { unsigned short u[4]; uint2 v; } pk;
#pragma unroll
    for (int r = 0; r < 4; ++r) pk.u[r] = (unsigned short)f2bf(d[r] * c0n);
    int o = w * 16 + ra;
    *(uint2*)(Ybf + (((size_t)b * 16 + kb) * 80 + o) * 32 + jbase + g * 4) = pk.v;
  }
  // Ybf rows 64 (c0n*mc), 65 (c0n*dg) + zero pads 66..79, this chunk's 16 cols
  if (t < 16) {
    Ybf[(((size_t)b * 16 + kb) * 80 + 64) * 32 + jbase + t] =
        (unsigned short)f2bf(sMc[t] * c0n);
  } else if (t < 32) {
    Ybf[(((size_t)b * 16 + kb) * 80 + 65) * 32 + jbase + (t - 16)] =
        (unsigned short)f2bf(sDg[t - 16] * c0n);
  } else if (t < 32 + 224) {
    int u2 = t - 32;
    int row = 66 + (u2 >> 4), col = jbase + (u2 & 15);
    Ybf[(((size_t)b * 16 + kb) * 80 + row) * 32 + col] = 0;
  }
  __syncthreads();

  if (t < 32) {
    float s1 = 0.f, s2 = 0.f;
#pragma unroll
    for (int r = 0; r < 16; ++r) {
      float xv = sXc[r][t];
      s1 += xv;
      s2 += sVec[r] * xv;
    }
    pmX[((size_t)b * 32 + ch) * 32 + t] = s1;
    ptC[((size_t)b * 32 + ch) * 32 + t] = s2;
  } else if (t < 35) {
    float s = 0.f;
    if (t == 32) { for (int r = 0; r < 16; ++r) s += sVec[r]; }
    if (t == 33) { for (int r = 0; r < 16; ++r) s += sVec[r] * sMc[r]; }
    if (t == 34) { for (int r = 0; r < 16; ++r) s += sVec[r] * sDg[r]; }
    pS[((size_t)b * 32 + ch) * 3 + (t - 32)] = s;
  }
}

// ---------------- KW: finalize stats -> colv, sconst. grid (16) ----------------
__global__ __launch_bounds__(256) void kW(
    const float* __restrict__ cf, const float* __restrict__ W1,
    const float* __restrict__ W2, const float* __restrict__ pA,
    const float* __restrict__ pD, const float* __restrict__ pmX,
    const float* __restrict__ ptC, const float* __restrict__ pS,
    float* __restrict__ colv, float* __restrict__ sconst) {
  int gb = blockIdx.x, t = threadIdx.x;
  int bb0 = gb * 4;
  __shared__ float sW1[64][69], sW2[64][69];
  __shared__ float mXs[4][33], tCs[4][33];
  __shared__ float scal[4][6];
  __shared__ float scf[69];
  if (t < 69) scf[t] = cf[t];
  for (int idx = t; idx < 64 * XN; idx += 256) {
    int r = idx / XN, c = idx - r * XN;
    sW1[r][c] = W1[idx];
    sW2[r][c] = W2[idx];
  }
  if (t < 128) {
    int bb = t >> 5, c = t & 31, b = bb0 + bb;
    float s1 = 0.f, s2 = 0.f;
#pragma unroll
    for (int k = 0; k < 32; ++k) {
      s1 += pmX[((size_t)b * 32 + k) * 32 + c];
      s2 += ptC[((size_t)b * 32 + k) * 32 + c];
    }
    mXs[bb][c] = s1 * (1.0f / NN);
    tCs[bb][c] = s2;
  } else if (t < 132) {
    int bb = t - 128, b = bb0 + bb;
    float sA = 0.f, sD = 0.f;
#pragma unroll
    for (int k = 0; k < 32; ++k) { sA += pA[b * 32 + k]; sD += pD[b * 32 + k]; }
    scal[bb][0] = sD * (1.0f / NN);
    scal[bb][1] = sA * (1.0f / ((float)NN * (float)NN));
  } else if (t < 136) {
    int bb = t - 132, b = bb0 + bb;
    float s1 = 0.f, s2 = 0.f, s3 = 0.f;
#pragma unroll
    for (int k = 0; k < 32; ++k) {
      s1 += pS[((size_t)b * 32 + k) * 3 + 0];
      s2 += pS[((size_t)b * 32 + k) * 3 + 1];
      s3 += pS[((size_t)b * 32 + k) * 3 + 2];
    }
    scal[bb][2] = s1; scal[bb][3] = s2; scal[bb][4] = s3;
  }
  __syncthreads();
  if (t < 4) {
    float s7 = 0.f;
#pragma unroll
    for (int c = 0; c < CI; ++c) s7 += scf[5 + CI + c] * mXs[t][c];
    sconst[bb0 + t] = scf[1] * scal[t][1] + scf[2] * scal[t][0] + s7;
  }
  {
    int bb = t >> 6, o = t & 63, b = bb0 + bb;
    float w1mX = 0.f, a1 = 0.f, a2 = 0.f, wt = 0.f;
#pragma unroll
    for (int c = 0; c < CI; ++c) {
      float m = mXs[bb][c];
      w1mX += sW1[o][c] * m;
      a1 += sW1[o][CI + c] * m;
      a2 += sW2[o][CI + c] * m;
      wt += sW1[o][c] * tCs[bb][c];
    }
    float smd = scal[bb][0], sma = scal[bb][1];
    a1 += sW1[o][66] * smd + sW1[o][67] * sma;
    a2 += sW2[o][66] * smd + sW2[o][67] * sma;
    float we0 = sW1[o][64], we1 = sW1[o][65];
    float S1n = w1mX + a1 + we0 * sma + we1 * smd;
    float SVn = (wt + a1 * scal[bb][2] + we0 * scal[bb][3] + we1 * scal[bb][4]) * (1.0f / NN);
    float4 cva = make_float4(S1n, a2 + SVn, sW2[o][64] + scf[0] * a1, sW2[o][65]);
    float4 cvb = make_float4(we0, we1, 0.f, 0.f);
    *(float4*)&colv[((size_t)b * CO + o) * 8] = cva;
    *(float4*)&colv[((size_t)b * CO + o) * 8 + 4] = cvb;
  }
}

// ---------------- K5 v7: direct fragment-linear global->VGPR, no staging, 1 barrier ----------------
// grid (8, NB), 512 threads = 8 waves = 4 row-groups (rg) x 2 K-halves (kh).
// Every operand load is a contiguous 16B/lane (1KB/wave) bf16x8 — single-line, pipelined by
// the compiler with counted vmcnt; no per-chunk barriers, so no vmcnt(0) drains.
__global__ __launch_bounds__(512, 4) void k5_mfma(
    const unsigned short* __restrict__ Abf, const unsigned short* __restrict__ Ybf,
    const float* __restrict__ X, const float* __restrict__ W2,
    const float* __restrict__ vec, const float* __restrict__ mc,
    const float* __restrict__ dg, const float* __restrict__ colv,
    const float* __restrict__ sconst, float* __restrict__ out) {
  int ic = blockIdx.x, b = blockIdx.y;
  int t = threadIdx.x, w = t >> 6, lane = t & 63;
  int rg = w >> 1, kh = w & 1;
  int ra = lane & 15, kg = lane >> 4, g = lane >> 4;
  int i0 = ic * 64, wr0 = rg * 16;
  __shared__ float sAcc[4][16][64];   // 16KB: kh==1 partials
  __shared__ float sG4[4][16][2];

  const unsigned short* Asrc = Abf + ((size_t)(b * 8 + ic)) * 8 * 4096;
  const unsigned short* Bsrc = Ybf + (size_t)b * 16 * 80 * 32;

  int arow = wr0 + ra, abase = arow * 64, aswz = arow & 7;

  f32x4 acc[4] = {{0.f, 0.f, 0.f, 0.f}, {0.f, 0.f, 0.f, 0.f},
                  {0.f, 0.f, 0.f, 0.f}, {0.f, 0.f, 0.f, 0.f}};
  f32x4 acc4 = {0.f, 0.f, 0.f, 0.f};

#pragma unroll
  for (int jt = 0; jt < 8; ++jt) {
    int jj = kh * 8 + jt;            // global K=32 slice 0..15
    int c = jj >> 1, kbl = jj & 1;
    bf16x8 af = *(const bf16x8*)&Asrc[(size_t)c * 4096 + abase +
                                      (((kbl * 4 + kg) ^ aswz) << 3)];
    const unsigned short* Bb = Bsrc + (size_t)jj * 80 * 32;
#pragma unroll
    for (int to = 0; to < 4; ++to) {
      bf16x8 bf = *(const bf16x8*)&Bb[(to * 16 + ra) * 32 + kg * 8];
      acc[to] = __builtin_amdgcn_mfma_f32_16x16x32_bf16(af, bf, acc[to], 0, 0, 0);
    }
    bf16x8 bf4 = *(const bf16x8*)&Bb[(64 + ra) * 32 + kg * 8];
    acc4 = __builtin_amdgcn_mfma_f32_16x16x32_bf16(af, bf4, acc4, 0, 0, 0);
  }

  if (kh == 1) {  // publish K-half partials
#pragma unroll
    for (int to = 0; to < 4; ++to)
#pragma unroll
      for (int r = 0; r < 4; ++r)
        sAcc[rg][g * 4 + r][to * 16 + ra] = acc[to][r];
    if (ra < 2) {
#pragma unroll
      for (int r = 0; r < 4; ++r) sG4[rg][g * 4 + r][ra] = acc4[r];
    }
  }
  __syncthreads();  // the ONLY barrier

  if (kh == 0) {
#pragma unroll
    for (int to = 0; to < 4; ++to)
#pragma unroll
      for (int r = 0; r < 4; ++r)
        acc[to][r] += sAcc[rg][g * 4 + r][to * 16 + ra];
    if (ra < 2) {
#pragma unroll
      for (int r = 0; r < 4; ++r) acc4[r] += sG4[rg][g * 4 + r][ra];
    }

    {  // fused X*W2c k-step (unscaled)
      const float* xp = X + (size_t)(b * NN + i0 + wr0 + ra) * CI + kg * 8;
      bf16x8 xf = cvt8(*(const float4*)xp, *(const float4*)(xp + 4));
#pragma unroll
      for (int to = 0; to < 4; ++to) {
        const float* wp = W2 + (size_t)(to * 16 + ra) * XN + kg * 8;
        bf16x8 wf = cvt8(*(const float4*)wp, *(const float4*)(wp + 4));
        acc[to] = __builtin_amdgcn_mfma_f32_16x16x32_bf16(xf, wf, acc[to], 0, 0, 0);
      }
    }

    // Gm/Gd broadcast from cols 0/1 of acc4 (summed on lanes ra<2)
    float Gm[4], Gd[4];
#pragma unroll
    for (int r = 0; r < 4; ++r) {
      Gm[r] = __shfl(acc4[r], lane & 48, 64);
      Gd[r] = __shfl(acc4[r], (lane & 48) | 1, 64);
    }

    float4 v4 = *(const float4*)&vec[b * NN + i0 + wr0 + g * 4];
    float4 m4 = *(const float4*)&mc[b * NN + i0 + wr0 + g * 4];
    float4 d4 = *(const float4*)&dg[b * NN + i0 + wr0 + g * 4];
    float sc = sconst[b];
    float vp[4] = {v4.x + sc, v4.y + sc, v4.z + sc, v4.w + sc};
    float mr[4] = {m4.x, m4.y, m4.z, m4.w};
    float dr[4] = {d4.x, d4.y, d4.z, d4.w};

#pragma unroll
    for (int to = 0; to < 4; ++to) {
      int o = to * 16 + ra;
      float4 cva = *(const float4*)&colv[((size_t)b * CO + o) * 8];
      float4 cvb = *(const float4*)&colv[((size_t)b * CO + o) * 8 + 4];
#pragma unroll
      for (int r = 0; r < 4; ++r) {
        float val = acc[to][r] + vp[r] * cva.x + cva.y + mr[r] * cva.z +
                    dr[r] * cva.w + Gm[r] * cvb.x + Gd[r] * cvb.y;
        out[((size_t)(b * NN + i0 + wr0 + g * 4 + r)) * CO + o] = val;
      }
    }
  }
}

extern "C" void kernel_launch(void* const* d_in, const int* in_sizes, int n_in,
                              void* d_out, int out_size, void* d_ws, size_t ws_size,
                              hipStream_t stream) {
  const float* A = (const float*)d_in[0];
  const float* X = (const float*)d_in[1];
  const float* cf = (const float*)d_in[2];
  const float* W1 = (const float*)d_in[3];
  const float* W2 = (const float*)d_in[4];
  float* out = (float*)d_out;

  float* p = (float*)d_ws;
  float* mc = p;      p += NB * NN;
  float* dg = p;      p += NB * NN;
  float* vec = p;     p += NB * NN;
  float* pA = p;      p += NB * 32;
  float* pD = p;      p += NB * 32;
  float* pmX = p;     p += NB * 32 * 32;
  float* ptC = p;     p += NB * 32 * 32;
  float* pS = p;      p += NB * 32 * 3;
  float* colv = p;    p += NB * CO * 8;
  float* sconst = p;  p += NB;
  unsigned short* Ybf = (unsigned short*)p;
  unsigned short* Abf = Ybf + (size_t)NB * 16 * 80 * 32;

  k1x<<<dim3(NB, 32), 256, 0, stream>>>(A, X, cf, W1, mc, dg, vec,
                                        pA, pD, pmX, ptC, pS, Ybf, Abf);
  kW<<<16, 256, 0, stream>>>(cf, W1, W2, pA, pD, pmX, ptC, pS, colv, sconst);
  k5_mfma<<<dim3(8, NB), 512, 0, stream>>>(Abf, Ybf, X, W2, vec, mc, dg,
                                           colv, sconst, out);
}

// Round 17
// 47.301 us; speedup vs baseline: 1.9015x; 1.0029x over previous
//
#include <hip/hip_runtime.h>
#include <hip/hip_bf16.h>

#define NB 64
#define NN 512
#define CI 32
#define CO 64
#define XN 68
// Ybf layout: [b][kb=0..15][row=0..79][32], bf16, pre-scaled by c0/n.
// Abf layout: [b][ic=0..7][c=0..7][4096], bf16(A) in k5 fragment-linear order:
//   element (local row r 0..63, kk 0..63) at r*64 + (((kk>>3) ^ (r&7))<<3) + (kk&7).

typedef __attribute__((ext_vector_type(8))) short bf16x8;
typedef __attribute__((ext_vector_type(4))) float f32x4;

__device__ inline short f2bf(float f) {
  union { __hip_bfloat16 h; unsigned short u; } cv;
  cv.h = __float2bfloat16(f);
  return (short)cv.u;
}

__device__ inline bf16x8 cvt8(float4 a, float4 b) {
  bf16x8 r;
  r[0] = f2bf(a.x); r[1] = f2bf(a.y); r[2] = f2bf(a.z); r[3] = f2bf(a.w);
  r[4] = f2bf(b.x); r[5] = f2bf(b.y); r[6] = f2bf(b.z); r[7] = f2bf(b.w);
  return r;
}

// ---------------- K1X: A row stats + X stats + Ybf chunk + Abf. grid (NB,32) ----------------
__global__ __launch_bounds__(256) void k1x(
    const float* __restrict__ A, const float* __restrict__ X,
    const float* __restrict__ cf, const float* __restrict__ W1,
    float* __restrict__ mc, float* __restrict__ dg, float* __restrict__ vec,
    float* __restrict__ pA, float* __restrict__ pD,
    float* __restrict__ pmX, float* __restrict__ ptC, float* __restrict__ pS,
    unsigned short* __restrict__ Ybf, unsigned short* __restrict__ Abf) {
  int b = blockIdx.x, ch = blockIdx.y;
  int t = threadIdx.x, w = t >> 6, lane = t & 63;
  int r0 = ch * 16;
  int kb = r0 >> 5, jbase = r0 & 16;
  const float* Ab = A + (size_t)b * NN * NN;
  __shared__ float sXc[16][33];
  __shared__ float scf[69];
  __shared__ float sMc[16], sDg[16], sVec[16], wsum[4];

  if (t < 69) scf[t] = cf[t];
  {  // stage X chunk: 16 rows x 32 cols
    int j = t >> 4, c = (t & 15) * 2;
    float2 xv = *(const float2*)(X + ((size_t)b * NN + r0 + j) * CI + c);
    sXc[j][c] = xv.x; sXc[j][c + 1] = xv.y;
  }
  float4 v0[4], v1[4];
#pragma unroll
  for (int m = 0; m < 4; ++m) {
    const float* rp = Ab + (size_t)(r0 + w * 4 + m) * NN;
    v0[m] = *(const float4*)(rp + lane * 4);
    v1[m] = *(const float4*)(rp + 256 + lane * 4);
  }
  float accR = 0.f;
#pragma unroll
  for (int m = 0; m < 4; ++m) {
    float s = (v0[m].x + v0[m].y) + (v0[m].z + v0[m].w) +
              (v1[m].x + v1[m].y) + (v1[m].z + v1[m].w);
#pragma unroll
    for (int off = 1; off < 64; off <<= 1) s += __shfl_xor(s, off, 64);
    if (lane == 0) {
      float m_ = s * (1.0f / NN);
      mc[b * NN + r0 + w * 4 + m] = m_;
      sMc[w * 4 + m] = m_;
    }
    accR += s;
  }
  if (lane == 0) wsum[w] = accR;
  if (t < 16) {
    float d = Ab[(size_t)(r0 + t) * NN + r0 + t];
    dg[b * NN + r0 + t] = d;
    sDg[t] = d;
  }

  {  // Abf: bf16(A) in k5-fragment-linear order
    int ic5 = ch >> 2;
    int lrb = (ch & 3) * 16 + w * 4;
    size_t bb = ((size_t)(b * 8 + ic5)) * 8 * 4096;
    int c5a = lane >> 4;
    int Ka = (lane & 15) >> 1;
    int sub = (lane & 1) << 2;
#pragma unroll
    for (int m = 0; m < 4; ++m) {
      int lr = lrb + m;
      int sl = ((Ka ^ (lr & 7)) << 3) + sub;
      union { unsigned short u[4]; uint2 v; } p0, p1;
      p0.u[0] = (unsigned short)f2bf(v0[m].x); p0.u[1] = (unsigned short)f2bf(v0[m].y);
      p0.u[2] = (unsigned short)f2bf(v0[m].z); p0.u[3] = (unsigned short)f2bf(v0[m].w);
      p1.u[0] = (unsigned short)f2bf(v1[m].x); p1.u[1] = (unsigned short)f2bf(v1[m].y);
      p1.u[2] = (unsigned short)f2bf(v1[m].z); p1.u[3] = (unsigned short)f2bf(v1[m].w);
      *(uint2*)(Abf + bb + (size_t)c5a * 4096 + lr * 64 + sl) = p0.v;
      *(uint2*)(Abf + bb + (size_t)(4 + c5a) * 4096 + lr * 64 + sl) = p1.v;
    }
  }
  __syncthreads();

  float c0n = scf[0] * (1.0f / NN);

  if (t < 16) {
    float u = 0.f;
#pragma unroll
    for (int c = 0; c < CI; ++c) u += scf[5 + c] * sXc[t][c];
    float vj = scf[3] * sMc[t] + scf[4] * sDg[t] + u;
    vec[b * NN + r0 + t] = vj;
    sVec[t] = vj;
  } else if (t == 16) {
    pA[b * 32 + ch] = wsum[0] + wsum[1] + wsum[2] + wsum[3];
    float sd = 0.f;
#pragma unroll
    for (int k = 0; k < 16; ++k) sd += sDg[k];
    pD[b * 32 + ch] = sd;
  }

  {  // Y chunk via MFMA (scaled by c0/n): wave w -> rows o = w*16..+15, cols r0..+15
    int ra = lane & 15, kg = lane >> 4, g = lane >> 4;
    const float* wp = W1 + (w * 16 + ra) * XN + kg * 8;
    bf16x8 wf = cvt8(*(const float4*)wp, *(const float4*)(wp + 4));
    const float* xp = &sXc[ra][kg * 8];
    bf16x8 xf = cvt8(*(const float4*)xp, *(const float4*)(xp + 4));
    f32x4 zero = {0.f, 0.f, 0.f, 0.f};
    f32x4 d = __builtin_amdgcn_mfma_f32_16x16x32_bf16(xf, wf, zero, 0, 0, 0);
    union { unsigned short u[4]; uint2 v; } pk;
#pragma unroll
    for (int r = 0; r < 4; ++r) pk.u[r] = (unsigned short)f2bf(d[r] * c0n);
    int o = w * 16 + ra;
    *(uint2*)(Ybf + (((size_t)b * 16 + kb) * 80 + o) * 32 + jbase + g * 4) = pk.v;
  }
  // Ybf rows 64 (c0n*mc), 65 (c0n*dg) + zero pads 66..79, this chunk's 16 cols
  if (t < 16) {
    Ybf[(((size_t)b * 16 + kb) * 80 + 64) * 32 + jbase + t] =
        (unsigned short)f2bf(sMc[t] * c0n);
  } else if (t < 32) {
    Ybf[(((size_t)b * 16 + kb) * 80 + 65) * 32 + jbase + (t - 16)] =
        (unsigned short)f2bf(sDg[t - 16] * c0n);
  } else if (t < 32 + 224) {
    int u2 = t - 32;
    int row = 66 + (u2 >> 4), col = jbase + (u2 & 15);
    Ybf[(((size_t)b * 16 + kb) * 80 + row) * 32 + col] = 0;
  }
  __syncthreads();

  if (t < 32) {
    float s1 = 0.f, s2 = 0.f;
#pragma unroll
    for (int r = 0; r < 16; ++r) {
      float xv = sXc[r][t];
      s1 += xv;
      s2 += sVec[r] * xv;
    }
    pmX[((size_t)b * 32 + ch) * 32 + t] = s1;
    ptC[((size_t)b * 32 + ch) * 32 + t] = s2;
  } else if (t < 35) {
    float s = 0.f;
    if (t == 32) { for (int r = 0; r < 16; ++r) s += sVec[r]; }
    if (t == 33) { for (int r = 0; r < 16; ++r) s += sVec[r] * sMc[r]; }
    if (t == 34) { for (int r = 0; r < 16; ++r) s += sVec[r] * sDg[r]; }
    pS[((size_t)b * 32 + ch) * 3 + (t - 32)] = s;
  }
}

// ---------------- KW: finalize stats -> colv, sconst. grid (16) ----------------
__global__ __launch_bounds__(256) void kW(
    const float* __restrict__ cf, const float* __restrict__ W1,
    const float* __restrict__ W2, const float* __restrict__ pA,
    const float* __restrict__ pD, const float* __restrict__ pmX,
    const float* __restrict__ ptC, const float* __restrict__ pS,
    float* __restrict__ colv, float* __restrict__ sconst) {
  int gb = blockIdx.x, t = threadIdx.x;
  int bb0 = gb * 4;
  __shared__ float sW1[64][69], sW2[64][69];
  __shared__ float mXs[4][33], tCs[4][33];
  __shared__ float scal[4][6];
  __shared__ float scf[69];
  if (t < 69) scf[t] = cf[t];
  for (int idx = t; idx < 64 * XN; idx += 256) {
    int r = idx / XN, c = idx - r * XN;
    sW1[r][c] = W1[idx];
    sW2[r][c] = W2[idx];
  }
  if (t < 128) {
    int bb = t >> 5, c = t & 31, b = bb0 + bb;
    float s1 = 0.f, s2 = 0.f;
#pragma unroll
    for (int k = 0; k < 32; ++k) {
      s1 += pmX[((size_t)b * 32 + k) * 32 + c];
      s2 += ptC[((size_t)b * 32 + k) * 32 + c];
    }
    mXs[bb][c] = s1 * (1.0f / NN);
    tCs[bb][c] = s2;
  } else if (t < 132) {
    int bb = t - 128, b = bb0 + bb;
    float sA = 0.f, sD = 0.f;
#pragma unroll
    for (int k = 0; k < 32; ++k) { sA += pA[b * 32 + k]; sD += pD[b * 32 + k]; }
    scal[bb][0] = sD * (1.0f / NN);
    scal[bb][1] = sA * (1.0f / ((float)NN * (float)NN));
  } else if (t < 136) {
    int bb = t - 132, b = bb0 + bb;
    float s1 = 0.f, s2 = 0.f, s3 = 0.f;
#pragma unroll
    for (int k = 0; k < 32; ++k) {
      s1 += pS[((size_t)b * 32 + k) * 3 + 0];
      s2 += pS[((size_t)b * 32 + k) * 3 + 1];
      s3 += pS[((size_t)b * 32 + k) * 3 + 2];
    }
    scal[bb][2] = s1; scal[bb][3] = s2; scal[bb][4] = s3;
  }
  __syncthreads();
  if (t < 4) {
    float s7 = 0.f;
#pragma unroll
    for (int c = 0; c < CI; ++c) s7 += scf[5 + CI + c] * mXs[t][c];
    sconst[bb0 + t] = scf[1] * scal[t][1] + scf[2] * scal[t][0] + s7;
  }
  {
    int bb = t >> 6, o = t & 63, b = bb0 + bb;
    float w1mX = 0.f, a1 = 0.f, a2 = 0.f, wt = 0.f;
#pragma unroll
    for (int c = 0; c < CI; ++c) {
      float m = mXs[bb][c];
      w1mX += sW1[o][c] * m;
      a1 += sW1[o][CI + c] * m;
      a2 += sW2[o][CI + c] * m;
      wt += sW1[o][c] * tCs[bb][c];
    }
    float smd = scal[bb][0], sma = scal[bb][1];
    a1 += sW1[o][66] * smd + sW1[o][67] * sma;
    a2 += sW2[o][66] * smd + sW2[o][67] * sma;
    float we0 = sW1[o][64], we1 = sW1[o][65];
    float S1n = w1mX + a1 + we0 * sma + we1 * smd;
    float SVn = (wt + a1 * scal[bb][2] + we0 * scal[bb][3] + we1 * scal[bb][4]) * (1.0f / NN);
    float4 cva = make_float4(S1n, a2 + SVn, sW2[o][64] + scf[0] * a1, sW2[o][65]);
    float4 cvb = make_float4(we0, we1, 0.f, 0.f);
    *(float4*)&colv[((size_t)b * CO + o) * 8] = cva;
    *(float4*)&colv[((size_t)b * CO + o) * 8 + 4] = cvb;
  }
}

// ---------------- K5 v8: manual 2-deep register pipeline, loads-before-MFMA pinned ----------------
// grid (8, NB), 512 threads = 8 waves = 4 row-groups (rg) x 2 K-halves (kh).
__global__ __launch_bounds__(512, 4) void k5_mfma(
    const unsigned short* __restrict__ Abf, const unsigned short* __restrict__ Ybf,
    const float* __restrict__ X, const float* __restrict__ W2,
    const float* __restrict__ vec, const float* __restrict__ mc,
    const float* __restrict__ dg, const float* __restrict__ colv,
    const float* __restrict__ sconst, float* __restrict__ out) {
  int ic = blockIdx.x, b = blockIdx.y;
  int t = threadIdx.x, w = t >> 6, lane = t & 63;
  int rg = w >> 1, kh = w & 1;
  int ra = lane & 15, kg = lane >> 4, g = lane >> 4;
  int i0 = ic * 64, wr0 = rg * 16;
  __shared__ float sAcc[4][16][64];
  __shared__ float sG4[4][16][2];

  const unsigned short* Asrc = Abf + ((size_t)(b * 8 + ic)) * 8 * 4096;
  const unsigned short* Bsrc = Ybf + (size_t)b * 16 * 80 * 32;

  int arow = wr0 + ra, abase = arow * 64, aswz = arow & 7;

#define APTR(jj) ((const bf16x8*)&Asrc[(size_t)((jj) >> 1) * 4096 + abase + \
                                       ((((((jj) & 1) << 2) + kg) ^ aswz) << 3)])
#define BPTR(jj, row) ((const bf16x8*)&Bsrc[(size_t)(jj) * 2560 + (row) * 32 + kg * 8])

  f32x4 acc[4] = {{0.f, 0.f, 0.f, 0.f}, {0.f, 0.f, 0.f, 0.f},
                  {0.f, 0.f, 0.f, 0.f}, {0.f, 0.f, 0.f, 0.f}};
  f32x4 acc4 = {0.f, 0.f, 0.f, 0.f};

  int jj0 = kh * 8;
  bf16x8 afc = *APTR(jj0);
  bf16x8 b0c = *BPTR(jj0, ra);
  bf16x8 b1c = *BPTR(jj0, 16 + ra);
  bf16x8 b2c = *BPTR(jj0, 32 + ra);
  bf16x8 b3c = *BPTR(jj0, 48 + ra);
  bf16x8 b4c = *BPTR(jj0, 64 + ra);

#pragma unroll
  for (int jt = 0; jt < 8; ++jt) {
    bf16x8 afn = afc, b0n = b0c, b1n = b1c, b2n = b2c, b3n = b3c, b4n = b4c;
    if (jt < 7) {  // issue next-step loads BEFORE this step's MFMAs
      int jn = kh * 8 + jt + 1;
      afn = *APTR(jn);
      b0n = *BPTR(jn, ra);
      b1n = *BPTR(jn, 16 + ra);
      b2n = *BPTR(jn, 32 + ra);
      b3n = *BPTR(jn, 48 + ra);
      b4n = *BPTR(jn, 64 + ra);
    }
    __builtin_amdgcn_sched_barrier(0);  // pin: loads above, MFMAs below
    acc[0] = __builtin_amdgcn_mfma_f32_16x16x32_bf16(afc, b0c, acc[0], 0, 0, 0);
    acc[1] = __builtin_amdgcn_mfma_f32_16x16x32_bf16(afc, b1c, acc[1], 0, 0, 0);
    acc[2] = __builtin_amdgcn_mfma_f32_16x16x32_bf16(afc, b2c, acc[2], 0, 0, 0);
    acc[3] = __builtin_amdgcn_mfma_f32_16x16x32_bf16(afc, b3c, acc[3], 0, 0, 0);
    acc4   = __builtin_amdgcn_mfma_f32_16x16x32_bf16(afc, b4c, acc4,   0, 0, 0);
    afc = afn; b0c = b0n; b1c = b1n; b2c = b2n; b3c = b3n; b4c = b4n;
  }
#undef APTR
#undef BPTR

  if (kh == 1) {  // publish K-half partials
#pragma unroll
    for (int to = 0; to < 4; ++to)
#pragma unroll
      for (int r = 0; r < 4; ++r)
        sAcc[rg][g * 4 + r][to * 16 + ra] = acc[to][r];
    if (ra < 2) {
#pragma unroll
      for (int r = 0; r < 4; ++r) sG4[rg][g * 4 + r][ra] = acc4[r];
    }
  }
  __syncthreads();  // the ONLY barrier

  if (kh == 0) {
#pragma unroll
    for (int to = 0; to < 4; ++to)
#pragma unroll
      for (int r = 0; r < 4; ++r)
        acc[to][r] += sAcc[rg][g * 4 + r][to * 16 + ra];
    if (ra < 2) {
#pragma unroll
      for (int r = 0; r < 4; ++r) acc4[r] += sG4[rg][g * 4 + r][ra];
    }

    {  // fused X*W2c k-step (unscaled)
      const float* xp = X + (size_t)(b * NN + i0 + wr0 + ra) * CI + kg * 8;
      bf16x8 xf = cvt8(*(const float4*)xp, *(const float4*)(xp + 4));
#pragma unroll
      for (int to = 0; to < 4; ++to) {
        const float* wp = W2 + (size_t)(to * 16 + ra) * XN + kg * 8;
        bf16x8 wf = cvt8(*(const float4*)wp, *(const float4*)(wp + 4));
        acc[to] = __builtin_amdgcn_mfma_f32_16x16x32_bf16(xf, wf, acc[to], 0, 0, 0);
      }
    }

    // Gm/Gd broadcast from cols 0/1 of acc4
    float Gm[4], Gd[4];
#pragma unroll
    for (int r = 0; r < 4; ++r) {
      Gm[r] = __shfl(acc4[r], lane & 48, 64);
      Gd[r] = __shfl(acc4[r], (lane & 48) | 1, 64);
    }

    float4 v4 = *(const float4*)&vec[b * NN + i0 + wr0 + g * 4];
    float4 m4 = *(const float4*)&mc[b * NN + i0 + wr0 + g * 4];
    float4 d4 = *(const float4*)&dg[b * NN + i0 + wr0 + g * 4];
    float sc = sconst[b];
    float vp[4] = {v4.x + sc, v4.y + sc, v4.z + sc, v4.w + sc};
    float mr[4] = {m4.x, m4.y, m4.z, m4.w};
    float dr[4] = {d4.x, d4.y, d4.z, d4.w};

#pragma unroll
    for (int to = 0; to < 4; ++to) {
      int o = to * 16 + ra;
      float4 cva = *(const float4*)&colv[((size_t)b * CO + o) * 8];
      float4 cvb = *(const float4*)&colv[((size_t)b * CO + o) * 8 + 4];
#pragma unroll
      for (int r = 0; r < 4; ++r) {
        float val = acc[to][r] + vp[r] * cva.x + cva.y + mr[r] * cva.z +
                    dr[r] * cva.w + Gm[r] * cvb.x + Gd[r] * cvb.y;
        out[((size_t)(b * NN + i0 + wr0 + g * 4 + r)) * CO + o] = val;
      }
    }
  }
}

extern "C" void kernel_launch(void* const* d_in, const int* in_sizes, int n_in,
                              void* d_out, int out_size, void* d_ws, size_t ws_size,
                              hipStream_t stream) {
  const float* A = (const float*)d_in[0];
  const float* X = (const float*)d_in[1];
  const float* cf = (const float*)d_in[2];
  const float* W1 = (const float*)d_in[3];
  const float* W2 = (const float*)d_in[4];
  float* out = (float*)d_out;

  float* p = (float*)d_ws;
  float* mc = p;      p += NB * NN;
  float* dg = p;      p += NB * NN;
  float* vec = p;     p += NB * NN;
  float* pA = p;      p += NB * 32;
  float* pD = p;      p += NB * 32;
  float* pmX = p;     p += NB * 32 * 32;
  float* ptC = p;     p += NB * 32 * 32;
  float* pS = p;      p += NB * 32 * 3;
  float* colv = p;    p += NB * CO * 8;
  float* sconst = p;  p += NB;
  unsigned short* Ybf = (unsigned short*)p;
  unsigned short* Abf = Ybf + (size_t)NB * 16 * 80 * 32;

  k1x<<<dim3(NB, 32), 256, 0, stream>>>(A, X, cf, W1, mc, dg, vec,
                                        pA, pD, pmX, ptC, pS, Ybf, Abf);
  kW<<<16, 256, 0, stream>>>(cf, W1, W2, pA, pD, pmX, ptC, pS, colv, sconst);
  k5_mfma<<<dim3(8, NB), 512, 0, stream>>>(Abf, Ybf, X, W2, vec, mc, dg,
                                           colv, sconst, out);
}

// Round 20
// 45.893 us; speedup vs baseline: 1.9598x; 1.0307x over previous
//
#include <hip/hip_runtime.h>
#include <hip/hip_bf16.h>

#define NB 64
#define NN 512
#define CI 32
#define CO 64
#define XN 68
// Ybf layout: [b][kb=0..15][row=0..79][k%32], bf16, pre-scaled by c0/n.
// rows 0..63 = Y (= c0n * X@W1c^T), 64 = c0n*mc, 65 = c0n*dg, 66..79 = 0.

typedef __attribute__((ext_vector_type(8))) short bf16x8;
typedef __attribute__((ext_vector_type(4))) float f32x4;

__device__ inline short f2bf(float f) {
  union { __hip_bfloat16 h; unsigned short u; } cv;
  cv.h = __float2bfloat16(f);
  return (short)cv.u;
}

__device__ inline bf16x8 cvt8(float4 a, float4 b) {
  bf16x8 r;
  r[0] = f2bf(a.x); r[1] = f2bf(a.y); r[2] = f2bf(a.z); r[3] = f2bf(a.w);
  r[4] = f2bf(b.x); r[5] = f2bf(b.y); r[6] = f2bf(b.z); r[7] = f2bf(b.w);
  return r;
}

// ---------------- K1X: A row stats + X stats + Ybf chunk. grid (NB,32) ----------------
__global__ __launch_bounds__(256) void k1x(
    const float* __restrict__ A, const float* __restrict__ X,
    const float* __restrict__ cf, const float* __restrict__ W1,
    float* __restrict__ mc, float* __restrict__ dg, float* __restrict__ vec,
    float* __restrict__ pA, float* __restrict__ pD,
    float* __restrict__ pmX, float* __restrict__ ptC, float* __restrict__ pS,
    unsigned short* __restrict__ Ybf) {
  int b = blockIdx.x, ch = blockIdx.y;
  int t = threadIdx.x, w = t >> 6, lane = t & 63;
  int r0 = ch * 16;
  int kb = r0 >> 5, jbase = r0 & 16;   // this chunk's 16 cols inside kb
  const float* Ab = A + (size_t)b * NN * NN;
  __shared__ float sXc[16][33];
  __shared__ float scf[69];
  __shared__ float sMc[16], sDg[16], sVec[16], wsum[4];

  if (t < 69) scf[t] = cf[t];
  {  // stage X chunk: 16 rows x 32 cols
    int j = t >> 4, c = (t & 15) * 2;
    float2 xv = *(const float2*)(X + ((size_t)b * NN + r0 + j) * CI + c);
    sXc[j][c] = xv.x; sXc[j][c + 1] = xv.y;
  }
  float4 v0[4], v1[4];
#pragma unroll
  for (int m = 0; m < 4; ++m) {
    const float* rp = Ab + (size_t)(r0 + w * 4 + m) * NN;
    v0[m] = *(const float4*)(rp + lane * 4);
    v1[m] = *(const float4*)(rp + 256 + lane * 4);
  }
  float accR = 0.f;
#pragma unroll
  for (int m = 0; m < 4; ++m) {
    float s = (v0[m].x + v0[m].y) + (v0[m].z + v0[m].w) +
              (v1[m].x + v1[m].y) + (v1[m].z + v1[m].w);
#pragma unroll
    for (int off = 1; off < 64; off <<= 1) s += __shfl_xor(s, off, 64);
    if (lane == 0) {
      float m_ = s * (1.0f / NN);
      mc[b * NN + r0 + w * 4 + m] = m_;
      sMc[w * 4 + m] = m_;
    }
    accR += s;
  }
  if (lane == 0) wsum[w] = accR;
  if (t < 16) {
    float d = Ab[(size_t)(r0 + t) * NN + r0 + t];
    dg[b * NN + r0 + t] = d;
    sDg[t] = d;
  }
  __syncthreads();  // sXc, sMc, sDg, wsum, scf ready

  float c0n = scf[0] * (1.0f / NN);

  if (t < 16) {  // vec for this chunk's 16 rows
    float u = 0.f;
#pragma unroll
    for (int c = 0; c < CI; ++c) u += scf[5 + c] * sXc[t][c];
    float vj = scf[3] * sMc[t] + scf[4] * sDg[t] + u;
    vec[b * NN + r0 + t] = vj;
    sVec[t] = vj;
  } else if (t == 16) {
    pA[b * 32 + ch] = wsum[0] + wsum[1] + wsum[2] + wsum[3];
    float sd = 0.f;
#pragma unroll
    for (int k = 0; k < 16; ++k) sd += sDg[k];
    pD[b * 32 + ch] = sd;
  }

  {  // Y chunk via MFMA (scaled by c0/n): wave w -> rows o = w*16..+15, cols r0..+15
    int ra = lane & 15, kg = lane >> 4, g = lane >> 4;
    const float* wp = W1 + (w * 16 + ra) * XN + kg * 8;
    bf16x8 wf = cvt8(*(const float4*)wp, *(const float4*)(wp + 4));
    const float* xp = &sXc[ra][kg * 8];
    bf16x8 xf = cvt8(*(const float4*)xp, *(const float4*)(xp + 4));
    f32x4 zero = {0.f, 0.f, 0.f, 0.f};
    f32x4 d = __builtin_amdgcn_mfma_f32_16x16x32_bf16(xf, wf, zero, 0, 0, 0);
    union { unsigned short u[4]; uint2 v; } pk;
#pragma unroll
    for (int r = 0; r < 4; ++r) pk.u[r] = (unsigned short)f2bf(d[r] * c0n);
    int o = w * 16 + ra;
    *(uint2*)(Ybf + (((size_t)b * 16 + kb) * 80 + o) * 32 + jbase + g * 4) = pk.v;
  }
  // Ybf rows 64 (c0n*mc), 65 (c0n*dg) + zero pads 66..79, this chunk's 16 cols
  if (t < 16) {
    Ybf[(((size_t)b * 16 + kb) * 80 + 64) * 32 + jbase + t] =
        (unsigned short)f2bf(sMc[t] * c0n);
  } else if (t < 32) {
    Ybf[(((size_t)b * 16 + kb) * 80 + 65) * 32 + jbase + (t - 16)] =
        (unsigned short)f2bf(sDg[t - 16] * c0n);
  } else if (t < 32 + 224) {
    int u2 = t - 32;
    int row = 66 + (u2 >> 4), col = jbase + (u2 & 15);
    Ybf[(((size_t)b * 16 + kb) * 80 + row) * 32 + col] = 0;
  }
  __syncthreads();  // sVec ready

  if (t < 32) {  // column partials over this chunk
    float s1 = 0.f, s2 = 0.f;
#pragma unroll
    for (int r = 0; r < 16; ++r) {
      float xv = sXc[r][t];
      s1 += xv;
      s2 += sVec[r] * xv;
    }
    pmX[((size_t)b * 32 + ch) * 32 + t] = s1;
    ptC[((size_t)b * 32 + ch) * 32 + t] = s2;
  } else if (t < 35) {
    float s = 0.f;
    if (t == 32) { for (int r = 0; r < 16; ++r) s += sVec[r]; }
    if (t == 33) { for (int r = 0; r < 16; ++r) s += sVec[r] * sMc[r]; }
    if (t == 34) { for (int r = 0; r < 16; ++r) s += sVec[r] * sDg[r]; }
    pS[((size_t)b * 32 + ch) * 3 + (t - 32)] = s;
  }
}

// ---------------- KW: finalize stats -> colv, sconst. grid (16) ----------------
__global__ __launch_bounds__(256) void kW(
    const float* __restrict__ cf, const float* __restrict__ W1,
    const float* __restrict__ W2, const float* __restrict__ pA,
    const float* __restrict__ pD, const float* __restrict__ pmX,
    const float* __restrict__ ptC, const float* __restrict__ pS,
    float* __restrict__ colv, float* __restrict__ sconst) {
  int gb = blockIdx.x, t = threadIdx.x;
  int bb0 = gb * 4;
  __shared__ float sW1[64][69], sW2[64][69];
  __shared__ float mXs[4][33], tCs[4][33];
  __shared__ float scal[4][6];
  __shared__ float scf[69];
  if (t < 69) scf[t] = cf[t];
  for (int idx = t; idx < 64 * XN; idx += 256) {
    int r = idx / XN, c = idx - r * XN;
    sW1[r][c] = W1[idx];
    sW2[r][c] = W2[idx];
  }
  if (t < 128) {
    int bb = t >> 5, c = t & 31, b = bb0 + bb;
    float s1 = 0.f, s2 = 0.f;
#pragma unroll
    for (int k = 0; k < 32; ++k) {
      s1 += pmX[((size_t)b * 32 + k) * 32 + c];
      s2 += ptC[((size_t)b * 32 + k) * 32 + c];
    }
    mXs[bb][c] = s1 * (1.0f / NN);
    tCs[bb][c] = s2;
  } else if (t < 132) {
    int bb = t - 128, b = bb0 + bb;
    float sA = 0.f, sD = 0.f;
#pragma unroll
    for (int k = 0; k < 32; ++k) { sA += pA[b * 32 + k]; sD += pD[b * 32 + k]; }
    scal[bb][0] = sD * (1.0f / NN);
    scal[bb][1] = sA * (1.0f / ((float)NN * (float)NN));
  } else if (t < 136) {
    int bb = t - 132, b = bb0 + bb;
    float s1 = 0.f, s2 = 0.f, s3 = 0.f;
#pragma unroll
    for (int k = 0; k < 32; ++k) {
      s1 += pS[((size_t)b * 32 + k) * 3 + 0];
      s2 += pS[((size_t)b * 32 + k) * 3 + 1];
      s3 += pS[((size_t)b * 32 + k) * 3 + 2];
    }
    scal[bb][2] = s1; scal[bb][3] = s2; scal[bb][4] = s3;
  }
  __syncthreads();
  if (t < 4) {
    float s7 = 0.f;
#pragma unroll
    for (int c = 0; c < CI; ++c) s7 += scf[5 + CI + c] * mXs[t][c];
    sconst[bb0 + t] = scf[1] * scal[t][1] + scf[2] * scal[t][0] + s7;
  }
  {
    int bb = t >> 6, o = t & 63, b = bb0 + bb;
    float w1mX = 0.f, a1 = 0.f, a2 = 0.f, wt = 0.f;
#pragma unroll
    for (int c = 0; c < CI; ++c) {
      float m = mXs[bb][c];
      w1mX += sW1[o][c] * m;
      a1 += sW1[o][CI + c] * m;
      a2 += sW2[o][CI + c] * m;
      wt += sW1[o][c] * tCs[bb][c];
    }
    float smd = scal[bb][0], sma = scal[bb][1];
    a1 += sW1[o][66] * smd + sW1[o][67] * sma;
    a2 += sW2[o][66] * smd + sW2[o][67] * sma;
    float we0 = sW1[o][64], we1 = sW1[o][65];
    float S1n = w1mX + a1 + we0 * sma + we1 * smd;
    float SVn = (wt + a1 * scal[bb][2] + we0 * scal[bb][3] + we1 * scal[bb][4]) * (1.0f / NN);
    float4 cva = make_float4(S1n, a2 + SVn, sW2[o][64] + scf[0] * a1, sW2[o][65]);
    float4 cvb = make_float4(we0, we1, 0.f, 0.f);
    *(float4*)&colv[((size_t)b * CO + o) * 8] = cva;
    *(float4*)&colv[((size_t)b * CO + o) * 8 + 4] = cvb;
  }
}

// ---------------- K5 v4b: LDS-staged A AND B, 64-row tile, 8 waves. grid (8, NB) ----------------
// 512 threads = 8 waves = 4 row-groups (rg, 16 rows each) x 2 col-halves (oc, 32 o each).
// Deltas vs v4: launch_bounds(512,2) (no VGPR spill risk), sched_barrier after load issue.
__global__ __launch_bounds__(512, 2) void k5_mfma(
    const float* __restrict__ A, const unsigned short* __restrict__ Ybf,
    const float* __restrict__ X, const float* __restrict__ W2,
    const float* __restrict__ vec, const float* __restrict__ mc,
    const float* __restrict__ dg, const float* __restrict__ colv,
    const float* __restrict__ sconst, float* __restrict__ out) {
  int ic = blockIdx.x, b = blockIdx.y;
  int t = threadIdx.x, w = t >> 6, lane = t & 63;
  int rg = w >> 1, oc = w & 1;
  int ra = lane & 15, kg = lane >> 4, g = lane >> 4;
  int i0 = ic * 64;
  int wr0 = rg * 16;
  __shared__ unsigned short sA[2][64 * 64];     // A bf16, XOR-swizzled 16B slots
  __shared__ unsigned short sB[2][160 * 40];    // B rows @ 80B stride (2-way only)
  __shared__ float sGm[64], sGd[64];

  const unsigned short* Yb = Ybf + (size_t)b * 16 * 80 * 32;

  // A staging: thread t -> row t>>3 (64 rows), k-slot t&7 (8 f32 = 32B contiguous)
  int st_r = t >> 3, st_k = t & 7;
  const float* Agl = A + ((size_t)(b * NN + i0 + st_r)) * NN + st_k * 8;
  int st_addr = st_r * 64 + ((st_k ^ (st_r & 7)) << 3);

  // B staging: chunk = 160 linear rows of 32 ushort (two kb panels, contiguous).
  int b1_row = t >> 2, b1_sub = t & 3;
  int b2_row = 128 + (t >> 2), b2_sub = t & 3;

  {  // prologue: stage chunk 0
    float4 a0 = *(const float4*)(Agl);
    float4 a1 = *(const float4*)(Agl + 4);
    *(bf16x8*)&sA[0][st_addr] = cvt8(a0, a1);
    uint4 v1 = *(const uint4*)(Yb + b1_row * 32 + b1_sub * 8);
    *(uint4*)&sB[0][b1_row * 40 + b1_sub * 8] = v1;
    if (t < 128) {
      uint4 v2 = *(const uint4*)(Yb + b2_row * 32 + b2_sub * 8);
      *(uint4*)&sB[0][b2_row * 40 + b2_sub * 8] = v2;
    }
  }
  __syncthreads();

  f32x4 acc[2] = {{0.f, 0.f, 0.f, 0.f}, {0.f, 0.f, 0.f, 0.f}};
  f32x4 acc4 = {0.f, 0.f, 0.f, 0.f};
  int arow = wr0 + ra;
  int abase = arow * 64;
  int aswz = arow & 7;

  for (int c = 0; c < 8; ++c) {
    int cur = c & 1;
    float4 na0, na1;
    uint4 nb1, nb2;
    if (c < 7) {  // issue next-chunk loads early (hide under MFMA)
      na0 = *(const float4*)(Agl + (c + 1) * 64);
      na1 = *(const float4*)(Agl + (c + 1) * 64 + 4);
      const unsigned short* nsrc = Yb + (size_t)(c + 1) * 160 * 32;
      nb1 = *(const uint4*)(nsrc + b1_row * 32 + b1_sub * 8);
      if (t < 128) nb2 = *(const uint4*)(nsrc + b2_row * 32 + b2_sub * 8);
    }
    __builtin_amdgcn_sched_barrier(0);  // keep the loads issued above the MFMAs
#pragma unroll
    for (int kbl = 0; kbl < 2; ++kbl) {
      bf16x8 af = *(const bf16x8*)&sA[cur][abase + (((kbl * 4 + kg) ^ aswz) << 3)];
#pragma unroll
      for (int to = 0; to < 2; ++to) {
        int grow = kbl * 80 + oc * 32 + to * 16 + ra;
        bf16x8 bf = *(const bf16x8*)&sB[cur][grow * 40 + kg * 8];
        acc[to] = __builtin_amdgcn_mfma_f32_16x16x32_bf16(af, bf, acc[to], 0, 0, 0);
      }
      if (oc == 0) {
        bf16x8 bf4 = *(const bf16x8*)&sB[cur][(kbl * 80 + 64 + ra) * 40 + kg * 8];
        acc4 = __builtin_amdgcn_mfma_f32_16x16x32_bf16(af, bf4, acc4, 0, 0, 0);
      }
    }
    if (c < 7) {  // write next chunk into the other buffer
      *(bf16x8*)&sA[cur ^ 1][st_addr] = cvt8(na0, na1);
      *(uint4*)&sB[cur ^ 1][b1_row * 40 + b1_sub * 8] = nb1;
      if (t < 128) *(uint4*)&sB[cur ^ 1][b2_row * 40 + b2_sub * 8] = nb2;
    }
    __syncthreads();
  }

  {  // fused X*W2c k-step (unscaled)
    const float* xp = X + (size_t)(b * NN + i0 + wr0 + ra) * CI + kg * 8;
    bf16x8 xf = cvt8(*(const float4*)xp, *(const float4*)(xp + 4));
#pragma unroll
    for (int to = 0; to < 2; ++to) {
      const float* wp = W2 + (size_t)(oc * 32 + to * 16 + ra) * XN + kg * 8;
      bf16x8 wf = cvt8(*(const float4*)wp, *(const float4*)(wp + 4));
      acc[to] = __builtin_amdgcn_mfma_f32_16x16x32_bf16(xf, wf, acc[to], 0, 0, 0);
    }
  }

  // share Gm/Gd (oc==0 waves; acc4 col 0 -> Gm, col 1 -> Gd)
  if (oc == 0 && ra < 2) {
#pragma unroll
    for (int r = 0; r < 4; ++r) {
      if (ra == 0) sGm[wr0 + g * 4 + r] = acc4[r];
      else         sGd[wr0 + g * 4 + r] = acc4[r];
    }
  }
  __syncthreads();

  // epilogue
  float4 v4 = *(const float4*)&vec[b * NN + i0 + wr0 + g * 4];
  float4 m4 = *(const float4*)&mc[b * NN + i0 + wr0 + g * 4];
  float4 d4 = *(const float4*)&dg[b * NN + i0 + wr0 + g * 4];
  float sc = sconst[b];
  float vp[4] = {v4.x + sc, v4.y + sc, v4.z + sc, v4.w + sc};
  float mr[4] = {m4.x, m4.y, m4.z, m4.w};
  float dr[4] = {d4.x, d4.y, d4.z, d4.w};
  float Gm[4], Gd[4];
#pragma unroll
  for (int r = 0; r < 4; ++r) {
    int row = wr0 + g * 4 + r;
    Gm[r] = sGm[row];
    Gd[r] = sGd[row];
  }

#pragma unroll
  for (int to = 0; to < 2; ++to) {
    int o = oc * 32 + to * 16 + ra;
    float4 cva = *(const float4*)&colv[((size_t)b * CO + o) * 8];
    float4 cvb = *(const float4*)&colv[((size_t)b * CO + o) * 8 + 4];
#pragma unroll
    for (int r = 0; r < 4; ++r) {
      float val = acc[to][r] + vp[r] * cva.x + cva.y + mr[r] * cva.z +
                  dr[r] * cva.w + Gm[r] * cvb.x + Gd[r] * cvb.y;
      out[((size_t)(b * NN + i0 + wr0 + g * 4 + r)) * CO + o] = val;
    }
  }
}

extern "C" void kernel_launch(void* const* d_in, const int* in_sizes, int n_in,
                              void* d_out, int out_size, void* d_ws, size_t ws_size,
                              hipStream_t stream) {
  const float* A = (const float*)d_in[0];
  const float* X = (const float*)d_in[1];
  const float* cf = (const float*)d_in[2];
  const float* W1 = (const float*)d_in[3];
  const float* W2 = (const float*)d_in[4];
  float* out = (float*)d_out;

  float* p = (float*)d_ws;
  float* mc = p;      p += NB * NN;
  float* dg = p;      p += NB * NN;
  float* vec = p;     p += NB * NN;
  float* pA = p;      p += NB * 32;
  float* pD = p;      p += NB * 32;
  float* pmX = p;     p += NB * 32 * 32;
  float* ptC = p;     p += NB * 32 * 32;
  float* pS = p;      p += NB * 32 * 3;
  float* colv = p;    p += NB * CO * 8;
  float* sconst = p;  p += NB;
  unsigned short* Ybf = (unsigned short*)p;

  k1x<<<dim3(NB, 32), 256, 0, stream>>>(A, X, cf, W1, mc, dg, vec,
                                        pA, pD, pmX, ptC, pS, Ybf);
  kW<<<16, 256, 0, stream>>>(cf, W1, W2, pA, pD, pmX, ptC, pS, colv, sconst);
  k5_mfma<<<dim3(8, NB), 512, 0, stream>>>(A, Ybf, X, W2, vec, mc, dg,
                                           colv, sconst, out);
}

// Round 21
// 45.806 us; speedup vs baseline: 1.9635x; 1.0019x over previous
//
#include <hip/hip_runtime.h>
#include <hip/hip_bf16.h>

#define NB 64
#define NN 512
#define CI 32
#define CO 64
#define XN 68
// Ybf layout: [b][kb=0..15][row=0..79][k%32], bf16, pre-scaled by c0/n.
// rows 0..63 = Y (= c0n * X@W1c^T), 64 = c0n*mc, 65 = c0n*dg, 66..79 = 0.

typedef __attribute__((ext_vector_type(8))) short bf16x8;
typedef __attribute__((ext_vector_type(4))) float f32x4;

__device__ inline short f2bf(float f) {
  union { __hip_bfloat16 h; unsigned short u; } cv;
  cv.h = __float2bfloat16(f);
  return (short)cv.u;
}

__device__ inline bf16x8 cvt8(float4 a, float4 b) {
  bf16x8 r;
  r[0] = f2bf(a.x); r[1] = f2bf(a.y); r[2] = f2bf(a.z); r[3] = f2bf(a.w);
  r[4] = f2bf(b.x); r[5] = f2bf(b.y); r[6] = f2bf(b.z); r[7] = f2bf(b.w);
  return r;
}

// ---------------- K1X: A row stats + X stats + Ybf chunk. grid (NB,32) ----------------
__global__ __launch_bounds__(256) void k1x(
    const float* __restrict__ A, const float* __restrict__ X,
    const float* __restrict__ cf, const float* __restrict__ W1,
    float* __restrict__ mc, float* __restrict__ dg, float* __restrict__ vec,
    float* __restrict__ pA, float* __restrict__ pD,
    float* __restrict__ pmX, float* __restrict__ ptC, float* __restrict__ pS,
    unsigned short* __restrict__ Ybf) {
  int b = blockIdx.x, ch = blockIdx.y;
  int t = threadIdx.x, w = t >> 6, lane = t & 63;
  int r0 = ch * 16;
  int kb = r0 >> 5, jbase = r0 & 16;   // this chunk's 16 cols inside kb
  const float* Ab = A + (size_t)b * NN * NN;
  __shared__ float sXc[16][33];
  __shared__ float scf[69];
  __shared__ float sMc[16], sDg[16], sVec[16], wsum[4];

  if (t < 69) scf[t] = cf[t];
  {  // stage X chunk: 16 rows x 32 cols
    int j = t >> 4, c = (t & 15) * 2;
    float2 xv = *(const float2*)(X + ((size_t)b * NN + r0 + j) * CI + c);
    sXc[j][c] = xv.x; sXc[j][c + 1] = xv.y;
  }
  float4 v0[4], v1[4];
#pragma unroll
  for (int m = 0; m < 4; ++m) {
    const float* rp = Ab + (size_t)(r0 + w * 4 + m) * NN;
    v0[m] = *(const float4*)(rp + lane * 4);
    v1[m] = *(const float4*)(rp + 256 + lane * 4);
  }
  float accR = 0.f;
#pragma unroll
  for (int m = 0; m < 4; ++m) {
    float s = (v0[m].x + v0[m].y) + (v0[m].z + v0[m].w) +
              (v1[m].x + v1[m].y) + (v1[m].z + v1[m].w);
#pragma unroll
    for (int off = 1; off < 64; off <<= 1) s += __shfl_xor(s, off, 64);
    if (lane == 0) {
      float m_ = s * (1.0f / NN);
      mc[b * NN + r0 + w * 4 + m] = m_;
      sMc[w * 4 + m] = m_;
    }
    accR += s;
  }
  if (lane == 0) wsum[w] = accR;
  if (t < 16) {
    float d = Ab[(size_t)(r0 + t) * NN + r0 + t];
    dg[b * NN + r0 + t] = d;
    sDg[t] = d;
  }
  __syncthreads();  // sXc, sMc, sDg, wsum, scf ready

  float c0n = scf[0] * (1.0f / NN);

  if (t < 16) {  // vec for this chunk's 16 rows
    float u = 0.f;
#pragma unroll
    for (int c = 0; c < CI; ++c) u += scf[5 + c] * sXc[t][c];
    float vj = scf[3] * sMc[t] + scf[4] * sDg[t] + u;
    vec[b * NN + r0 + t] = vj;
    sVec[t] = vj;
  } else if (t == 16) {
    pA[b * 32 + ch] = wsum[0] + wsum[1] + wsum[2] + wsum[3];
    float sd = 0.f;
#pragma unroll
    for (int k = 0; k < 16; ++k) sd += sDg[k];
    pD[b * 32 + ch] = sd;
  }

  {  // Y chunk via MFMA (scaled by c0/n): wave w -> rows o = w*16..+15, cols r0..+15
    int ra = lane & 15, kg = lane >> 4, g = lane >> 4;
    const float* wp = W1 + (w * 16 + ra) * XN + kg * 8;
    bf16x8 wf = cvt8(*(const float4*)wp, *(const float4*)(wp + 4));
    const float* xp = &sXc[ra][kg * 8];
    bf16x8 xf = cvt8(*(const float4*)xp, *(const float4*)(xp + 4));
    f32x4 zero = {0.f, 0.f, 0.f, 0.f};
    f32x4 d = __builtin_amdgcn_mfma_f32_16x16x32_bf16(xf, wf, zero, 0, 0, 0);
    union { unsigned short u[4]; uint2 v; } pk;
#pragma unroll
    for (int r = 0; r < 4; ++r) pk.u[r] = (unsigned short)f2bf(d[r] * c0n);
    int o = w * 16 + ra;
    *(uint2*)(Ybf + (((size_t)b * 16 + kb) * 80 + o) * 32 + jbase + g * 4) = pk.v;
  }
  // Ybf rows 64 (c0n*mc), 65 (c0n*dg) + zero pads 66..79, this chunk's 16 cols
  if (t < 16) {
    Ybf[(((size_t)b * 16 + kb) * 80 + 64) * 32 + jbase + t] =
        (unsigned short)f2bf(sMc[t] * c0n);
  } else if (t < 32) {
    Ybf[(((size_t)b * 16 + kb) * 80 + 65) * 32 + jbase + (t - 16)] =
        (unsigned short)f2bf(sDg[t - 16] * c0n);
  } else if (t < 32 + 224) {
    int u2 = t - 32;
    int row = 66 + (u2 >> 4), col = jbase + (u2 & 15);
    Ybf[(((size_t)b * 16 + kb) * 80 + row) * 32 + col] = 0;
  }
  __syncthreads();  // sVec ready

  if (t < 32) {  // column partials over this chunk
    float s1 = 0.f, s2 = 0.f;
#pragma unroll
    for (int r = 0; r < 16; ++r) {
      float xv = sXc[r][t];
      s1 += xv;
      s2 += sVec[r] * xv;
    }
    pmX[((size_t)b * 32 + ch) * 32 + t] = s1;
    ptC[((size_t)b * 32 + ch) * 32 + t] = s2;
  } else if (t < 35) {
    float s = 0.f;
    if (t == 32) { for (int r = 0; r < 16; ++r) s += sVec[r]; }
    if (t == 33) { for (int r = 0; r < 16; ++r) s += sVec[r] * sMc[r]; }
    if (t == 34) { for (int r = 0; r < 16; ++r) s += sVec[r] * sDg[r]; }
    pS[((size_t)b * 32 + ch) * 3 + (t - 32)] = s;
  }
}

// ---------------- KW: finalize stats -> colv, sconst. grid (16) ----------------
__global__ __launch_bounds__(256) void kW(
    const float* __restrict__ cf, const float* __restrict__ W1,
    const float* __restrict__ W2, const float* __restrict__ pA,
    const float* __restrict__ pD, const float* __restrict__ pmX,
    const float* __restrict__ ptC, const float* __restrict__ pS,
    float* __restrict__ colv, float* __restrict__ sconst) {
  int gb = blockIdx.x, t = threadIdx.x;
  int bb0 = gb * 4;
  __shared__ float sW1[64][69], sW2[64][69];
  __shared__ float mXs[4][33], tCs[4][33];
  __shared__ float scal[4][6];
  __shared__ float scf[69];
  if (t < 69) scf[t] = cf[t];
  for (int idx = t; idx < 64 * XN; idx += 256) {
    int r = idx / XN, c = idx - r * XN;
    sW1[r][c] = W1[idx];
    sW2[r][c] = W2[idx];
  }
  if (t < 128) {
    int bb = t >> 5, c = t & 31, b = bb0 + bb;
    float s1 = 0.f, s2 = 0.f;
#pragma unroll
    for (int k = 0; k < 32; ++k) {
      s1 += pmX[((size_t)b * 32 + k) * 32 + c];
      s2 += ptC[((size_t)b * 32 + k) * 32 + c];
    }
    mXs[bb][c] = s1 * (1.0f / NN);
    tCs[bb][c] = s2;
  } else if (t < 132) {
    int bb = t - 128, b = bb0 + bb;
    float sA = 0.f, sD = 0.f;
#pragma unroll
    for (int k = 0; k < 32; ++k) { sA += pA[b * 32 + k]; sD += pD[b * 32 + k]; }
    scal[bb][0] = sD * (1.0f / NN);
    scal[bb][1] = sA * (1.0f / ((float)NN * (float)NN));
  } else if (t < 136) {
    int bb = t - 132, b = bb0 + bb;
    float s1 = 0.f, s2 = 0.f, s3 = 0.f;
#pragma unroll
    for (int k = 0; k < 32; ++k) {
      s1 += pS[((size_t)b * 32 + k) * 3 + 0];
      s2 += pS[((size_t)b * 32 + k) * 3 + 1];
      s3 += pS[((size_t)b * 32 + k) * 3 + 2];
    }
    scal[bb][2] = s1; scal[bb][3] = s2; scal[bb][4] = s3;
  }
  __syncthreads();
  if (t < 4) {
    float s7 = 0.f;
#pragma unroll
    for (int c = 0; c < CI; ++c) s7 += scf[5 + CI + c] * mXs[t][c];
    sconst[bb0 + t] = scf[1] * scal[t][1] + scf[2] * scal[t][0] + s7;
  }
  {
    int bb = t >> 6, o = t & 63, b = bb0 + bb;
    float w1mX = 0.f, a1 = 0.f, a2 = 0.f, wt = 0.f;
#pragma unroll
    for (int c = 0; c < CI; ++c) {
      float m = mXs[bb][c];
      w1mX += sW1[o][c] * m;
      a1 += sW1[o][CI + c] * m;
      a2 += sW2[o][CI + c] * m;
      wt += sW1[o][c] * tCs[bb][c];
    }
    float smd = scal[bb][0], sma = scal[bb][1];
    a1 += sW1[o][66] * smd + sW1[o][67] * sma;
    a2 += sW2[o][66] * smd + sW2[o][67] * sma;
    float we0 = sW1[o][64], we1 = sW1[o][65];
    float S1n = w1mX + a1 + we0 * sma + we1 * smd;
    float SVn = (wt + a1 * scal[bb][2] + we0 * scal[bb][3] + we1 * scal[bb][4]) * (1.0f / NN);
    float4 cva = make_float4(S1n, a2 + SVn, sW2[o][64] + scf[0] * a1, sW2[o][65]);
    float4 cvb = make_float4(we0, we1, 0.f, 0.f);
    *(float4*)&colv[((size_t)b * CO + o) * 8] = cva;
    *(float4*)&colv[((size_t)b * CO + o) * 8 + 4] = cvb;
  }
}

// ---------------- K5 v4c: LDS-staged A+B, DEPTH-2 register prefetch. grid (8, NB) ----------------
// 512 threads = 8 waves = 4 row-groups (rg) x 2 col-halves (oc). Tile 64 i x 64 o.
// Loads for chunk c+2 are issued during chunk c; the ds_write of chunk c+1's registers
// therefore waits on loads a full iteration old -> vmcnt nearly drained (no ~500cy stall).
__global__ __launch_bounds__(512, 2) void k5_mfma(
    const float* __restrict__ A, const unsigned short* __restrict__ Ybf,
    const float* __restrict__ X, const float* __restrict__ W2,
    const float* __restrict__ vec, const float* __restrict__ mc,
    const float* __restrict__ dg, const float* __restrict__ colv,
    const float* __restrict__ sconst, float* __restrict__ out) {
  int ic = blockIdx.x, b = blockIdx.y;
  int t = threadIdx.x, w = t >> 6, lane = t & 63;
  int rg = w >> 1, oc = w & 1;
  int ra = lane & 15, kg = lane >> 4, g = lane >> 4;
  int i0 = ic * 64;
  int wr0 = rg * 16;
  __shared__ unsigned short sA[2][64 * 64];     // A bf16, XOR-swizzled 16B slots
  __shared__ unsigned short sB[2][160 * 40];    // B rows @ 80B stride (2-way only)
  __shared__ float sGm[64], sGd[64];

  const unsigned short* Yb = Ybf + (size_t)b * 16 * 80 * 32;

  // A staging: thread t -> row t>>3 (64 rows), k-slot t&7 (32B contiguous)
  int st_r = t >> 3, st_k = t & 7;
  const float* Agl = A + ((size_t)(b * NN + i0 + st_r)) * NN + st_k * 8;
  int st_addr = st_r * 64 + ((st_k ^ (st_r & 7)) << 3);

  // B staging: chunk = 160 linear rows of 32 ushort (two kb panels, contiguous).
  int b1_row = t >> 2, b1_sub = t & 3;
  int b2_row = 128 + (t >> 2), b2_sub = t & 3;
  bool hasb2 = (t < 128);

  // prologue: chunk 0 direct to LDS; chunk 1 into regC (stays in flight)
  {
    float4 a0 = *(const float4*)(Agl);
    float4 a1 = *(const float4*)(Agl + 4);
    *(bf16x8*)&sA[0][st_addr] = cvt8(a0, a1);
    uint4 v1 = *(const uint4*)(Yb + b1_row * 32 + b1_sub * 8);
    *(uint4*)&sB[0][b1_row * 40 + b1_sub * 8] = v1;
    if (hasb2) {
      uint4 v2 = *(const uint4*)(Yb + b2_row * 32 + b2_sub * 8);
      *(uint4*)&sB[0][b2_row * 40 + b2_sub * 8] = v2;
    }
  }
  float4 rCa0 = *(const float4*)(Agl + 64);
  float4 rCa1 = *(const float4*)(Agl + 64 + 4);
  uint4 rCb1 = *(const uint4*)(Yb + 160 * 32 + b1_row * 32 + b1_sub * 8);
  uint4 rCb2;
  if (hasb2) rCb2 = *(const uint4*)(Yb + 160 * 32 + b2_row * 32 + b2_sub * 8);
  __syncthreads();

  f32x4 acc[2] = {{0.f, 0.f, 0.f, 0.f}, {0.f, 0.f, 0.f, 0.f}};
  f32x4 acc4 = {0.f, 0.f, 0.f, 0.f};
  int arow = wr0 + ra;
  int abase = arow * 64;
  int aswz = arow & 7;

  for (int c = 0; c < 8; ++c) {
    int cur = c & 1;
    float4 rNa0, rNa1;
    uint4 rNb1, rNb2;
    if (c < 6) {  // far prefetch: chunk c+2
      rNa0 = *(const float4*)(Agl + (c + 2) * 64);
      rNa1 = *(const float4*)(Agl + (c + 2) * 64 + 4);
      const unsigned short* nsrc = Yb + (size_t)(c + 2) * 160 * 32;
      rNb1 = *(const uint4*)(nsrc + b1_row * 32 + b1_sub * 8);
      if (hasb2) rNb2 = *(const uint4*)(nsrc + b2_row * 32 + b2_sub * 8);
    }
    __builtin_amdgcn_sched_barrier(0);  // keep prefetch issue above the MFMAs
#pragma unroll
    for (int kbl = 0; kbl < 2; ++kbl) {
      bf16x8 af = *(const bf16x8*)&sA[cur][abase + (((kbl * 4 + kg) ^ aswz) << 3)];
#pragma unroll
      for (int to = 0; to < 2; ++to) {
        int grow = kbl * 80 + oc * 32 + to * 16 + ra;
        bf16x8 bf = *(const bf16x8*)&sB[cur][grow * 40 + kg * 8];
        acc[to] = __builtin_amdgcn_mfma_f32_16x16x32_bf16(af, bf, acc[to], 0, 0, 0);
      }
      if (oc == 0) {
        bf16x8 bf4 = *(const bf16x8*)&sB[cur][(kbl * 80 + 64 + ra) * 40 + kg * 8];
        acc4 = __builtin_amdgcn_mfma_f32_16x16x32_bf16(af, bf4, acc4, 0, 0, 0);
      }
    }
    if (c < 7) {  // write chunk c+1 (regC, issued one full iteration ago) into other buffer
      *(bf16x8*)&sA[cur ^ 1][st_addr] = cvt8(rCa0, rCa1);
      *(uint4*)&sB[cur ^ 1][b1_row * 40 + b1_sub * 8] = rCb1;
      if (hasb2) *(uint4*)&sB[cur ^ 1][b2_row * 40 + b2_sub * 8] = rCb2;
      rCa0 = rNa0; rCa1 = rNa1; rCb1 = rNb1;
      if (hasb2) rCb2 = rNb2;
    }
    __syncthreads();
  }

  {  // fused X*W2c k-step (unscaled)
    const float* xp = X + (size_t)(b * NN + i0 + wr0 + ra) * CI + kg * 8;
    bf16x8 xf = cvt8(*(const float4*)xp, *(const float4*)(xp + 4));
#pragma unroll
    for (int to = 0; to < 2; ++to) {
      const float* wp = W2 + (size_t)(oc * 32 + to * 16 + ra) * XN + kg * 8;
      bf16x8 wf = cvt8(*(const float4*)wp, *(const float4*)(wp + 4));
      acc[to] = __builtin_amdgcn_mfma_f32_16x16x32_bf16(xf, wf, acc[to], 0, 0, 0);
    }
  }

  // share Gm/Gd (oc==0 waves; acc4 col 0 -> Gm, col 1 -> Gd)
  if (oc == 0 && ra < 2) {
#pragma unroll
    for (int r = 0; r < 4; ++r) {
      if (ra == 0) sGm[wr0 + g * 4 + r] = acc4[r];
      else         sGd[wr0 + g * 4 + r] = acc4[r];
    }
  }
  __syncthreads();

  // epilogue
  float4 v4 = *(const float4*)&vec[b * NN + i0 + wr0 + g * 4];
  float4 m4 = *(const float4*)&mc[b * NN + i0 + wr0 + g * 4];
  float4 d4 = *(const float4*)&dg[b * NN + i0 + wr0 + g * 4];
  float sc = sconst[b];
  float vp[4] = {v4.x + sc, v4.y + sc, v4.z + sc, v4.w + sc};
  float mr[4] = {m4.x, m4.y, m4.z, m4.w};
  float dr[4] = {d4.x, d4.y, d4.z, d4.w};
  float Gm[4], Gd[4];
#pragma unroll
  for (int r = 0; r < 4; ++r) {
    int row = wr0 + g * 4 + r;
    Gm[r] = sGm[row];
    Gd[r] = sGd[row];
  }

#pragma unroll
  for (int to = 0; to < 2; ++to) {
    int o = oc * 32 + to * 16 + ra;
    float4 cva = *(const float4*)&colv[((size_t)b * CO + o) * 8];
    float4 cvb = *(const float4*)&colv[((size_t)b * CO + o) * 8 + 4];
#pragma unroll
    for (int r = 0; r < 4; ++r) {
      float val = acc[to][r] + vp[r] * cva.x + cva.y + mr[r] * cva.z +
                  dr[r] * cva.w + Gm[r] * cvb.x + Gd[r] * cvb.y;
      out[((size_t)(b * NN + i0 + wr0 + g * 4 + r)) * CO + o] = val;
    }
  }
}

extern "C" void kernel_launch(void* const* d_in, const int* in_sizes, int n_in,
                              void* d_out, int out_size, void* d_ws, size_t ws_size,
                              hipStream_t stream) {
  const float* A = (const float*)d_in[0];
  const float* X = (const float*)d_in[1];
  const float* cf = (const float*)d_in[2];
  const float* W1 = (const float*)d_in[3];
  const float* W2 = (const float*)d_in[4];
  float* out = (float*)d_out;

  float* p = (float*)d_ws;
  float* mc = p;      p += NB * NN;
  float* dg = p;      p += NB * NN;
  float* vec = p;     p += NB * NN;
  float* pA = p;      p += NB * 32;
  float* pD = p;      p += NB * 32;
  float* pmX = p;     p += NB * 32 * 32;
  float* ptC = p;     p += NB * 32 * 32;
  float* pS = p;      p += NB * 32 * 3;
  float* colv = p;    p += NB * CO * 8;
  float* sconst = p;  p += NB;
  unsigned short* Ybf = (unsigned short*)p;

  k1x<<<dim3(NB, 32), 256, 0, stream>>>(A, X, cf, W1, mc, dg, vec,
                                        pA, pD, pmX, ptC, pS, Ybf);
  kW<<<16, 256, 0, stream>>>(cf, W1, W2, pA, pD, pmX, ptC, pS, colv, sconst);
  k5_mfma<<<dim3(8, NB), 512, 0, stream>>>(A, Ybf, X, W2, vec, mc, dg,
                                           colv, sconst, out);
}

// Round 22
// 45.590 us; speedup vs baseline: 1.9728x; 1.0047x over previous
//
#include <hip/hip_runtime.h>
#include <hip/hip_bf16.h>

#define NB 64
#define NN 512
#define CI 32
#define CO 64
#define XN 68
// Ybf layout: [b][kb=0..15][row=0..79][32], bf16, pre-scaled by c0/n.
// Abf layout: [b][ic=0..7][c=0..7][4096], bf16(A), fragment-linear XOR-swizzled:
//   element (local row r 0..63, kk 0..63) at r*64 + (((kk>>3) ^ (r&7))<<3) + (kk&7).

typedef __attribute__((ext_vector_type(8))) short bf16x8;
typedef __attribute__((ext_vector_type(4))) float f32x4;

__device__ inline short f2bf(float f) {
  union { __hip_bfloat16 h; unsigned short u; } cv;
  cv.h = __float2bfloat16(f);
  return (short)cv.u;
}

__device__ inline bf16x8 cvt8(float4 a, float4 b) {
  bf16x8 r;
  r[0] = f2bf(a.x); r[1] = f2bf(a.y); r[2] = f2bf(a.z); r[3] = f2bf(a.w);
  r[4] = f2bf(b.x); r[5] = f2bf(b.y); r[6] = f2bf(b.z); r[7] = f2bf(b.w);
  return r;
}

// ---------------- K1X: A row stats + X stats + Ybf chunk + Abf. grid (NB,32) ----------------
__global__ __launch_bounds__(256) void k1x(
    const float* __restrict__ A, const float* __restrict__ X,
    const float* __restrict__ cf, const float* __restrict__ W1,
    float* __restrict__ mc, float* __restrict__ dg, float* __restrict__ vec,
    float* __restrict__ pA, float* __restrict__ pD,
    float* __restrict__ pmX, float* __restrict__ ptC, float* __restrict__ pS,
    unsigned short* __restrict__ Ybf, unsigned short* __restrict__ Abf) {
  int b = blockIdx.x, ch = blockIdx.y;
  int t = threadIdx.x, w = t >> 6, lane = t & 63;
  int r0 = ch * 16;
  int kb = r0 >> 5, jbase = r0 & 16;
  const float* Ab = A + (size_t)b * NN * NN;
  __shared__ float sXc[16][33];
  __shared__ float scf[69];
  __shared__ float sMc[16], sDg[16], sVec[16], wsum[4];

  if (t < 69) scf[t] = cf[t];
  {  // stage X chunk: 16 rows x 32 cols
    int j = t >> 4, c = (t & 15) * 2;
    float2 xv = *(const float2*)(X + ((size_t)b * NN + r0 + j) * CI + c);
    sXc[j][c] = xv.x; sXc[j][c + 1] = xv.y;
  }
  float4 v0[4], v1[4];
#pragma unroll
  for (int m = 0; m < 4; ++m) {
    const float* rp = Ab + (size_t)(r0 + w * 4 + m) * NN;
    v0[m] = *(const float4*)(rp + lane * 4);
    v1[m] = *(const float4*)(rp + 256 + lane * 4);
  }
  float accR = 0.f;
#pragma unroll
  for (int m = 0; m < 4; ++m) {
    float s = (v0[m].x + v0[m].y) + (v0[m].z + v0[m].w) +
              (v1[m].x + v1[m].y) + (v1[m].z + v1[m].w);
#pragma unroll
    for (int off = 1; off < 64; off <<= 1) s += __shfl_xor(s, off, 64);
    if (lane == 0) {
      float m_ = s * (1.0f / NN);
      mc[b * NN + r0 + w * 4 + m] = m_;
      sMc[w * 4 + m] = m_;
    }
    accR += s;
  }
  if (lane == 0) wsum[w] = accR;
  if (t < 16) {
    float d = Ab[(size_t)(r0 + t) * NN + r0 + t];
    dg[b * NN + r0 + t] = d;
    sDg[t] = d;
  }

  {  // Abf: bf16(A) in k5-fragment-linear order (local rows within 64-row tile)
    int ic5 = ch >> 2;
    int lrb = (ch & 3) * 16 + w * 4;
    size_t bb = ((size_t)(b * 8 + ic5)) * 8 * 4096;
    int c5a = lane >> 4;                 // chunk for cols 0..255
    int Ka = (lane & 15) >> 1;           // 8-elem slot
    int sub = (lane & 1) << 2;           // element offset within slot
#pragma unroll
    for (int m = 0; m < 4; ++m) {
      int lr = lrb + m;
      int sl = ((Ka ^ (lr & 7)) << 3) + sub;
      union { unsigned short u[4]; uint2 v; } p0, p1;
      p0.u[0] = (unsigned short)f2bf(v0[m].x); p0.u[1] = (unsigned short)f2bf(v0[m].y);
      p0.u[2] = (unsigned short)f2bf(v0[m].z); p0.u[3] = (unsigned short)f2bf(v0[m].w);
      p1.u[0] = (unsigned short)f2bf(v1[m].x); p1.u[1] = (unsigned short)f2bf(v1[m].y);
      p1.u[2] = (unsigned short)f2bf(v1[m].z); p1.u[3] = (unsigned short)f2bf(v1[m].w);
      *(uint2*)(Abf + bb + (size_t)c5a * 4096 + lr * 64 + sl) = p0.v;
      *(uint2*)(Abf + bb + (size_t)(4 + c5a) * 4096 + lr * 64 + sl) = p1.v;
    }
  }
  __syncthreads();  // sXc, sMc, sDg, wsum, scf ready

  float c0n = scf[0] * (1.0f / NN);

  if (t < 16) {  // vec for this chunk's 16 rows
    float u = 0.f;
#pragma unroll
    for (int c = 0; c < CI; ++c) u += scf[5 + c] * sXc[t][c];
    float vj = scf[3] * sMc[t] + scf[4] * sDg[t] + u;
    vec[b * NN + r0 + t] = vj;
    sVec[t] = vj;
  } else if (t == 16) {
    pA[b * 32 + ch] = wsum[0] + wsum[1] + wsum[2] + wsum[3];
    float sd = 0.f;
#pragma unroll
    for (int k = 0; k < 16; ++k) sd += sDg[k];
    pD[b * 32 + ch] = sd;
  }

  {  // Y chunk via MFMA (scaled by c0/n): wave w -> rows o = w*16..+15, cols r0..+15
    int ra = lane & 15, kg = lane >> 4, g = lane >> 4;
    const float* wp = W1 + (w * 16 + ra) * XN + kg * 8;
    bf16x8 wf = cvt8(*(const float4*)wp, *(const float4*)(wp + 4));
    const float* xp = &sXc[ra][kg * 8];
    bf16x8 xf = cvt8(*(const float4*)xp, *(const float4*)(xp + 4));
    f32x4 zero = {0.f, 0.f, 0.f, 0.f};
    f32x4 d = __builtin_amdgcn_mfma_f32_16x16x32_bf16(xf, wf, zero, 0, 0, 0);
    union { unsigned short u[4]; uint2 v; } pk;
#pragma unroll
    for (int r = 0; r < 4; ++r) pk.u[r] = (unsigned short)f2bf(d[r] * c0n);
    int o = w * 16 + ra;
    *(uint2*)(Ybf + (((size_t)b * 16 + kb) * 80 + o) * 32 + jbase + g * 4) = pk.v;
  }
  // Ybf rows 64 (c0n*mc), 65 (c0n*dg) + zero pads 66..79, this chunk's 16 cols
  if (t < 16) {
    Ybf[(((size_t)b * 16 + kb) * 80 + 64) * 32 + jbase + t] =
        (unsigned short)f2bf(sMc[t] * c0n);
  } else if (t < 32) {
    Ybf[(((size_t)b * 16 + kb) * 80 + 65) * 32 + jbase + (t - 16)] =
        (unsigned short)f2bf(sDg[t - 16] * c0n);
  } else if (t < 32 + 224) {
    int u2 = t - 32;
    int row = 66 + (u2 >> 4), col = jbase + (u2 & 15);
    Ybf[(((size_t)b * 16 + kb) * 80 + row) * 32 + col] = 0;
  }
  __syncthreads();  // sVec ready

  if (t < 32) {  // column partials over this chunk
    float s1 = 0.f, s2 = 0.f;
#pragma unroll
    for (int r = 0; r < 16; ++r) {
      float xv = sXc[r][t];
      s1 += xv;
      s2 += sVec[r] * xv;
    }
    pmX[((size_t)b * 32 + ch) * 32 + t] = s1;
    ptC[((size_t)b * 32 + ch) * 32 + t] = s2;
  } else if (t < 35) {
    float s = 0.f;
    if (t == 32) { for (int r = 0; r < 16; ++r) s += sVec[r]; }
    if (t == 33) { for (int r = 0; r < 16; ++r) s += sVec[r] * sMc[r]; }
    if (t == 34) { for (int r = 0; r < 16; ++r) s += sVec[r] * sDg[r]; }
    pS[((size_t)b * 32 + ch) * 3 + (t - 32)] = s;
  }
}

// ---------------- KW: finalize stats -> colv, sconst. grid (16) ----------------
__global__ __launch_bounds__(256) void kW(
    const float* __restrict__ cf, const float* __restrict__ W1,
    const float* __restrict__ W2, const float* __restrict__ pA,
    const float* __restrict__ pD, const float* __restrict__ pmX,
    const float* __restrict__ ptC, const float* __restrict__ pS,
    float* __restrict__ colv, float* __restrict__ sconst) {
  int gb = blockIdx.x, t = threadIdx.x;
  int bb0 = gb * 4;
  __shared__ float sW1[64][69], sW2[64][69];
  __shared__ float mXs[4][33], tCs[4][33];
  __shared__ float scal[4][6];
  __shared__ float scf[69];
  if (t < 69) scf[t] = cf[t];
  for (int idx = t; idx < 64 * XN; idx += 256) {
    int r = idx / XN, c = idx - r * XN;
    sW1[r][c] = W1[idx];
    sW2[r][c] = W2[idx];
  }
  if (t < 128) {
    int bb = t >> 5, c = t & 31, b = bb0 + bb;
    float s1 = 0.f, s2 = 0.f;
#pragma unroll
    for (int k = 0; k < 32; ++k) {
      s1 += pmX[((size_t)b * 32 + k) * 32 + c];
      s2 += ptC[((size_t)b * 32 + k) * 32 + c];
    }
    mXs[bb][c] = s1 * (1.0f / NN);
    tCs[bb][c] = s2;
  } else if (t < 132) {
    int bb = t - 128, b = bb0 + bb;
    float sA = 0.f, sD = 0.f;
#pragma unroll
    for (int k = 0; k < 32; ++k) { sA += pA[b * 32 + k]; sD += pD[b * 32 + k]; }
    scal[bb][0] = sD * (1.0f / NN);
    scal[bb][1] = sA * (1.0f / ((float)NN * (float)NN));
  } else if (t < 136) {
    int bb = t - 132, b = bb0 + bb;
    float s1 = 0.f, s2 = 0.f, s3 = 0.f;
#pragma unroll
    for (int k = 0; k < 32; ++k) {
      s1 += pS[((size_t)b * 32 + k) * 3 + 0];
      s2 += pS[((size_t)b * 32 + k) * 3 + 1];
      s3 += pS[((size_t)b * 32 + k) * 3 + 2];
    }
    scal[bb][2] = s1; scal[bb][3] = s2; scal[bb][4] = s3;
  }
  __syncthreads();
  if (t < 4) {
    float s7 = 0.f;
#pragma unroll
    for (int c = 0; c < CI; ++c) s7 += scf[5 + CI + c] * mXs[t][c];
    sconst[bb0 + t] = scf[1] * scal[t][1] + scf[2] * scal[t][0] + s7;
  }
  {
    int bb = t >> 6, o = t & 63, b = bb0 + bb;
    float w1mX = 0.f, a1 = 0.f, a2 = 0.f, wt = 0.f;
#pragma unroll
    for (int c = 0; c < CI; ++c) {
      float m = mXs[bb][c];
      w1mX += sW1[o][c] * m;
      a1 += sW1[o][CI + c] * m;
      a2 += sW2[o][CI + c] * m;
      wt += sW1[o][c] * tCs[bb][c];
    }
    float smd = scal[bb][0], sma = scal[bb][1];
    a1 += sW1[o][66] * smd + sW1[o][67] * sma;
    a2 += sW2[o][66] * smd + sW2[o][67] * sma;
    float we0 = sW1[o][64], we1 = sW1[o][65];
    float S1n = w1mX + a1 + we0 * sma + we1 * smd;
    float SVn = (wt + a1 * scal[bb][2] + we0 * scal[bb][3] + we1 * scal[bb][4]) * (1.0f / NN);
    float4 cva = make_float4(S1n, a2 + SVn, sW2[o][64] + scf[0] * a1, sW2[o][65]);
    float4 cvb = make_float4(we0, we1, 0.f, 0.f);
    *(float4*)&colv[((size_t)b * CO + o) * 8] = cva;
    *(float4*)&colv[((size_t)b * CO + o) * 8 + 4] = cvb;
  }
}

// ---------------- K5 v4d: A from bf16 Abf (L3-hot, linear copy), B LDS-staged ----------------
// grid (8, NB), 512 threads = 8 waves = 4 row-groups (rg) x 2 col-halves (oc).
// Depth-2 register prefetch (loads span a full chunk iteration before their ds_write).
__global__ __launch_bounds__(512, 2) void k5_mfma(
    const unsigned short* __restrict__ Abf, const unsigned short* __restrict__ Ybf,
    const float* __restrict__ X, const float* __restrict__ W2,
    const float* __restrict__ vec, const float* __restrict__ mc,
    const float* __restrict__ dg, const float* __restrict__ colv,
    const float* __restrict__ sconst, float* __restrict__ out) {
  int ic = blockIdx.x, b = blockIdx.y;
  int t = threadIdx.x, w = t >> 6, lane = t & 63;
  int rg = w >> 1, oc = w & 1;
  int ra = lane & 15, kg = lane >> 4, g = lane >> 4;
  int i0 = ic * 64;
  int wr0 = rg * 16;
  __shared__ unsigned short sA[2][4096];        // 8KB/buf, fragment-linear (pre-swizzled)
  __shared__ unsigned short sB[2][160 * 40];    // B rows @ 80B stride (2-way only)
  __shared__ float sGm[64], sGd[64];

  const unsigned short* Asrc = Abf + ((size_t)(b * 8 + ic)) * 8 * 4096;
  const unsigned short* Yb = Ybf + (size_t)b * 16 * 80 * 32;

  // B staging: chunk = 160 linear rows of 32 ushort (two kb panels, contiguous).
  int b1_row = t >> 2, b1_sub = t & 3;
  int b2_row = 128 + (t >> 2), b2_sub = t & 3;
  bool hasb2 = (t < 128);

  // prologue: chunk 0 direct to LDS; chunk 1 into regC (stays in flight)
  {
    uint4 av = *(const uint4*)(Asrc + t * 8);
    *(uint4*)&sA[0][t * 8] = av;
    uint4 v1 = *(const uint4*)(Yb + b1_row * 32 + b1_sub * 8);
    *(uint4*)&sB[0][b1_row * 40 + b1_sub * 8] = v1;
    if (hasb2) {
      uint4 v2 = *(const uint4*)(Yb + b2_row * 32 + b2_sub * 8);
      *(uint4*)&sB[0][b2_row * 40 + b2_sub * 8] = v2;
    }
  }
  uint4 rCa = *(const uint4*)(Asrc + 4096 + t * 8);
  uint4 rCb1 = *(const uint4*)(Yb + 160 * 32 + b1_row * 32 + b1_sub * 8);
  uint4 rCb2;
  if (hasb2) rCb2 = *(const uint4*)(Yb + 160 * 32 + b2_row * 32 + b2_sub * 8);
  __syncthreads();

  f32x4 acc[2] = {{0.f, 0.f, 0.f, 0.f}, {0.f, 0.f, 0.f, 0.f}};
  f32x4 acc4 = {0.f, 0.f, 0.f, 0.f};
  int arow = wr0 + ra;
  int abase = arow * 64;
  int aswz = arow & 7;

  for (int c = 0; c < 8; ++c) {
    int cur = c & 1;
    uint4 rNa, rNb1, rNb2;
    if (c < 6) {  // far prefetch: chunk c+2
      rNa = *(const uint4*)(Asrc + (size_t)(c + 2) * 4096 + t * 8);
      const unsigned short* nsrc = Yb + (size_t)(c + 2) * 160 * 32;
      rNb1 = *(const uint4*)(nsrc + b1_row * 32 + b1_sub * 8);
      if (hasb2) rNb2 = *(const uint4*)(nsrc + b2_row * 32 + b2_sub * 8);
    }
    __builtin_amdgcn_sched_barrier(0);  // keep prefetch issue above the MFMAs
#pragma unroll
    for (int kbl = 0; kbl < 2; ++kbl) {
      bf16x8 af = *(const bf16x8*)&sA[cur][abase + (((kbl * 4 + kg) ^ aswz) << 3)];
#pragma unroll
      for (int to = 0; to < 2; ++to) {
        int grow = kbl * 80 + oc * 32 + to * 16 + ra;
        bf16x8 bf = *(const bf16x8*)&sB[cur][grow * 40 + kg * 8];
        acc[to] = __builtin_amdgcn_mfma_f32_16x16x32_bf16(af, bf, acc[to], 0, 0, 0);
      }
      if (oc == 0) {
        bf16x8 bf4 = *(const bf16x8*)&sB[cur][(kbl * 80 + 64 + ra) * 40 + kg * 8];
        acc4 = __builtin_amdgcn_mfma_f32_16x16x32_bf16(af, bf4, acc4, 0, 0, 0);
      }
    }
    if (c < 7) {  // write chunk c+1 (regC, issued one full iteration ago)
      *(uint4*)&sA[cur ^ 1][t * 8] = rCa;
      *(uint4*)&sB[cur ^ 1][b1_row * 40 + b1_sub * 8] = rCb1;
      if (hasb2) *(uint4*)&sB[cur ^ 1][b2_row * 40 + b2_sub * 8] = rCb2;
      rCa = rNa; rCb1 = rNb1;
      if (hasb2) rCb2 = rNb2;
    }
    __syncthreads();
  }

  {  // fused X*W2c k-step (unscaled)
    const float* xp = X + (size_t)(b * NN + i0 + wr0 + ra) * CI + kg * 8;
    bf16x8 xf = cvt8(*(const float4*)xp, *(const float4*)(xp + 4));
#pragma unroll
    for (int to = 0; to < 2; ++to) {
      const float* wp = W2 + (size_t)(oc * 32 + to * 16 + ra) * XN + kg * 8;
      bf16x8 wf = cvt8(*(const float4*)wp, *(const float4*)(wp + 4));
      acc[to] = __builtin_amdgcn_mfma_f32_16x16x32_bf16(xf, wf, acc[to], 0, 0, 0);
    }
  }

  // share Gm/Gd (oc==0 waves; acc4 col 0 -> Gm, col 1 -> Gd)
  if (oc == 0 && ra < 2) {
#pragma unroll
    for (int r = 0; r < 4; ++r) {
      if (ra == 0) sGm[wr0 + g * 4 + r] = acc4[r];
      else         sGd[wr0 + g * 4 + r] = acc4[r];
    }
  }
  __syncthreads();

  // epilogue
  float4 v4 = *(const float4*)&vec[b * NN + i0 + wr0 + g * 4];
  float4 m4 = *(const float4*)&mc[b * NN + i0 + wr0 + g * 4];
  float4 d4 = *(const float4*)&dg[b * NN + i0 + wr0 + g * 4];
  float sc = sconst[b];
  float vp[4] = {v4.x + sc, v4.y + sc, v4.z + sc, v4.w + sc};
  float mr[4] = {m4.x, m4.y, m4.z, m4.w};
  float dr[4] = {d4.x, d4.y, d4.z, d4.w};
  float Gm[4], Gd[4];
#pragma unroll
  for (int r = 0; r < 4; ++r) {
    int row = wr0 + g * 4 + r;
    Gm[r] = sGm[row];
    Gd[r] = sGd[row];
  }

#pragma unroll
  for (int to = 0; to < 2; ++to) {
    int o = oc * 32 + to * 16 + ra;
    float4 cva = *(const float4*)&colv[((size_t)b * CO + o) * 8];
    float4 cvb = *(const float4*)&colv[((size_t)b * CO + o) * 8 + 4];
#pragma unroll
    for (int r = 0; r < 4; ++r) {
      float val = acc[to][r] + vp[r] * cva.x + cva.y + mr[r] * cva.z +
                  dr[r] * cva.w + Gm[r] * cvb.x + Gd[r] * cvb.y;
      out[((size_t)(b * NN + i0 + wr0 + g * 4 + r)) * CO + o] = val;
    }
  }
}

extern "C" void kernel_launch(void* const* d_in, const int* in_sizes, int n_in,
                              void* d_out, int out_size, void* d_ws, size_t ws_size,
                              hipStream_t stream) {
  const float* A = (const float*)d_in[0];
  const float* X = (const float*)d_in[1];
  const float* cf = (const float*)d_in[2];
  const float* W1 = (const float*)d_in[3];
  const float* W2 = (const float*)d_in[4];
  float* out = (float*)d_out;

  float* p = (float*)d_ws;
  float* mc = p;      p += NB * NN;
  float* dg = p;      p += NB * NN;
  float* vec = p;     p += NB * NN;
  float* pA = p;      p += NB * 32;
  float* pD = p;      p += NB * 32;
  float* pmX = p;     p += NB * 32 * 32;
  float* ptC = p;     p += NB * 32 * 32;
  float* pS = p;      p += NB * 32 * 3;
  float* colv = p;    p += NB * CO * 8;
  float* sconst = p;  p += NB;
  unsigned short* Ybf = (unsigned short*)p;
  unsigned short* Abf = Ybf + (size_t)NB * 16 * 80 * 32;

  k1x<<<dim3(NB, 32), 256, 0, stream>>>(A, X, cf, W1, mc, dg, vec,
                                        pA, pD, pmX, ptC, pS, Ybf, Abf);
  kW<<<16, 256, 0, stream>>>(cf, W1, W2, pA, pD, pmX, ptC, pS, colv, sconst);
  k5_mfma<<<dim3(8, NB), 512, 0, stream>>>(Abf, Ybf, X, W2, vec, mc, dg,
                                           colv, sconst, out);
}